// Round 7
// baseline (480.888 us; speedup 1.0000x reference)
//
#include <hip/hip_runtime.h>

typedef _Float16 half8  __attribute__((ext_vector_type(8)));
typedef _Float16 half4v __attribute__((ext_vector_type(4)));
typedef float  floatx4  __attribute__((ext_vector_type(4)));
typedef float  floatx2  __attribute__((ext_vector_type(2)));

#define MFMA16(A,B,C) __builtin_amdgcn_mfma_f32_16x16x32_f16((A),(B),(C),0,0,0)

#define L2E  1.4426950408889634f
#define L2E2 2.8853900817779268f

__device__ __forceinline__ float rcpf(float x){ return __builtin_amdgcn_rcpf(x); }
__device__ __forceinline__ float ex2(float x){ return __builtin_amdgcn_exp2f(x); }
__device__ __forceinline__ float tanh_raw(float c){
  return 1.0f - 2.0f*rcpf(1.0f + ex2(L2E2*c));
}
__device__ __forceinline__ half8 ld8(const _Float16* p){
  half4v a = *(const half4v*)p;
  half4v b = *(const half4v*)(p+4);
  return __builtin_shufflevector(a,b,0,1,2,3,4,5,6,7);
}

__device__ __forceinline__ floatx2 ex2v(floatx2 x){
  floatx2 r; r[0]=ex2(x[0]); r[1]=ex2(x[1]); return r;
}
__device__ __forceinline__ floatx2 rcpv(floatx2 x){
  floatx2 r; r[0]=rcpf(x[0]); r[1]=rcpf(x[1]); return r;
}

// Fused LSTM cell on a PAIR of cells (float2 ext-vector -> VOP3P
// v_pk_{add,mul,fma}_f32 for the non-trans arithmetic).
// 7 trans/cell (5 ex2 + 2 rcp), exact algebra:
//   c' = (c*P + (C-1)*Q) * rcp(P*Q),  h = (E-1)/((1+F)(1+E))
// with A=2^-yi B=2^-yf C=2^yg F=2^-yo E=2^(2L c'), P=(1+A)(1+C), Q=1+B.
__device__ __forceinline__ floatx2 lstm_cell2(floatx2 yi, floatx2 yf,
                                              floatx2 yg, floatx2 yo,
                                              floatx2& c){
  floatx2 A = ex2v(-yi), B = ex2v(-yf), C = ex2v(yg);
  const floatx2 one = {1.f, 1.f};
  floatx2 P = (one + A)*(one + C);
  floatx2 Q = one + B;
  floatx2 r = rcpv(P*Q);
  floatx2 cn = (c*P + (C - one)*Q)*r;
  c = cn;
  floatx2 F = ex2v(-yo), E = ex2v(L2E2*cn);
  floatx2 r3 = rcpv((one + F)*(one + E));
  return (E - one)*r3;
}

// grid geometry tables (compile-time foldable)
static __device__ constexpr int DY[27] = {0,0,0,0,0,0,0,0, 1,1,1,1,1,1,1,1, 2,2, 3,3,3,4,4,4,5,5,5};
static __device__ constexpr int DX[27] = {0,1,2,3,4,5,6,7, 0,1,2,3,4,5,6,7, 0,1, 3,4,5,3,4,5,3,4,5};
static __device__ constexpr int PY[9]  = {0,0,0,0,0,0,0,1,4};
static __device__ constexpr int PX[9]  = {1,2,3,4,5,6,7,0,4};
static __device__ constexpr int OY[46] = {0,0,0,0,0,0,0,0, 1,1,1,1,1,1,1,1, 2,2,2,2,2,2,2,2,
                                          3,3,3,3,3,3,3, 4,4,4,4,4, 5,5,5,5,5, 6,6,6,6,6};
static __device__ constexpr int OX[46] = {0,1,2,3,4,5,6,7, 0,1,2,3,4,5,6,7, 0,1,2,3,4,5,6,7,
                                          0,1,2,3,4,5,6, 2,3,4,5,6, 2,3,4,5,6, 2,3,4,5,6};
__device__ constexpr int d1idx(int iy,int ix){
  return (iy<0||iy>7||ix<0||ix>7) ? -1 :
         (iy<=1) ? iy*8+ix :
         (iy==2 && ix<=1) ? 16+ix :
         (iy>=3 && iy<=5 && ix>=3 && ix<=5) ? 18+(iy-3)*3+(ix-3) : -1;
}

// ---------------------------------------------------------------------------
// Combined encoder: batch-32 per block (two sequential 16-batch subtiles
// sharing ONE barrier per timestep), packed-pair cell (R6).
// R7: the 4 x-part weight fragments (bxp + g*136, loop-invariant wihb) are
// hoisted into registers before the t-loop — removes 4 ds_read_b128 +
// their lgkmcnt waits from every timestep's critical path.
// ---------------------------------------------------------------------------
__global__ __launch_bounds__(512, 4) void lstm_all(
    const float* __restrict__ target, const float* __restrict__ neigh,
    const float* __restrict__ e_wih, const float* __restrict__ e_whh,
    const float* __restrict__ e_bih, const float* __restrict__ e_bhh,
    const float* __restrict__ n_wih, const float* __restrict__ n_whh,
    const float* __restrict__ n_bih, const float* __restrict__ n_bhh,
    _Float16* __restrict__ h_enc16, _Float16* __restrict__ h_nb16)
{
  __shared__ _Float16 h_lds[2][32][136];
  __shared__ _Float16 xf16[32][168];
  __shared__ __align__(16) _Float16 wihb[8][4][17][8];

  const int tid  = threadIdx.x;
  const int wv   = tid >> 6;
  const int lane = tid & 63;
  const int q    = lane >> 4;
  const int cb   = lane & 15;

  const bool enc = (blockIdx.x < 256);
  const float* x   = enc ? target : neigh;
  const float* wih = enc ? e_wih : n_wih;
  const float* whh = enc ? e_whh : n_whh;
  const float* bih = enc ? e_bih : n_bih;
  const float* bhh = enc ? e_bhh : n_bhh;
  _Float16* hout   = enc ? h_enc16 : h_nb16;
  const long base  = enc ? (long)blockIdx.x*32 : (long)(blockIdx.x-256)*32;

  for (int i = tid; i < 32*168; i += 512){
    int seq = i/168, rem = i%168, t = rem>>3, f = rem&7;
    float v = 0.f;
    if (t < 20) v = (f < 7) ? x[base*140 + seq*140 + t*7 + f] : 1.0f;
    xf16[seq][rem] = (_Float16)v;
  }
  for (int i = tid; i < 32*136; i += 512) ((_Float16*)h_lds)[i] = (_Float16)0.f;

  if (q == 0){
    #pragma unroll
    for (int g=0; g<4; ++g){
      const float sc = (g==2) ? L2E2 : L2E;
      const int col = g*128 + wv*16 + cb;
      _Float16* d = &wihb[wv][g][cb][0];
      #pragma unroll
      for (int j=0;j<7;++j) d[j] = (_Float16)(wih[col*7+j]*sc);
      d[7] = (_Float16)((bih[col]+bhh[col])*sc);
    }
  } else if (lane == 16){
    #pragma unroll
    for (int g=0; g<4; ++g){
      _Float16* d = &wihb[wv][g][16][0];
      #pragma unroll
      for (int j=0;j<8;++j) d[j] = (_Float16)0.f;
    }
  }

  half8 bfrag[4][4];
  #pragma unroll
  for (int g=0; g<4; ++g){
    const float sc = (g==2) ? L2E2 : L2E;
    const int col = g*128 + wv*16 + cb;
    #pragma unroll
    for (int kc=0; kc<4; ++kc){
      const float* src = whh + (long)col*128 + kc*32 + q*8;
      half8 f;
      #pragma unroll
      for (int j=0;j<8;++j) f[j] = (_Float16)(src[j]*sc);
      bfrag[g][kc] = f;
    }
  }
  __syncthreads();

  const _Float16* bxp = &wihb[wv][0][(q==0)?cb:16][0];
  const _Float16* zsrc = &wihb[wv][0][16][0];
  const _Float16* a0p = (q==0) ? &xf16[cb][0]    : zsrc;
  const _Float16* a1p = (q==0) ? &xf16[cb+16][0] : zsrc;
  const int astep = (q==0) ? 8 : 0;
  half8 a40 = *(const half8*)a0p; a0p += astep;
  half8 a41 = *(const half8*)a1p; a1p += astep;

  // R7: loop-invariant x-part weight fragments in registers (16 VGPRs)
  half8 bxr[4];
  #pragma unroll
  for (int g=0; g<4; ++g) bxr[g] = *(const half8*)(bxp + g*136);

  floatx2 c0[2] = {{0,0},{0,0}}, c1[2] = {{0,0},{0,0}};
  half4v hv0 = {0,0,0,0}, hv1 = {0,0,0,0};
  const floatx4 ZERO4 = {0.f,0.f,0.f,0.f};

  for (int t=0; t<20; ++t){
    // ---- subtile 0 (batch rows cb) ----
    {
      const _Float16* hrow = &h_lds[t&1][cb][0];
      floatx4 acc[4];
      #pragma unroll
      for (int g=0; g<4; ++g)
        acc[g] = MFMA16(bxr[g], a40, ZERO4);
      #pragma unroll
      for (int kc=0; kc<4; ++kc){
        half8 b = *(const half8*)(hrow + kc*32 + q*8);
        #pragma unroll
        for (int g=0; g<4; ++g)
          acc[g] = MFMA16(bfrag[g][kc], b, acc[g]);
      }
      #pragma unroll
      for (int rp=0; rp<2; ++rp){
        floatx2 yi = {acc[0][2*rp], acc[0][2*rp+1]};
        floatx2 yf = {acc[1][2*rp], acc[1][2*rp+1]};
        floatx2 yg = {acc[2][2*rp], acc[2][2*rp+1]};
        floatx2 yo = {acc[3][2*rp], acc[3][2*rp+1]};
        floatx2 h2 = lstm_cell2(yi, yf, yg, yo, c0[rp]);
        hv0[2*rp]   = (_Float16)h2[0];
        hv0[2*rp+1] = (_Float16)h2[1];
      }
      *(half4v*)&h_lds[(t+1)&1][cb][wv*16 + q*4] = hv0;
    }
    // ---- subtile 1 (batch rows cb+16) ----
    {
      const _Float16* hrow = &h_lds[t&1][cb+16][0];
      floatx4 acc[4];
      #pragma unroll
      for (int g=0; g<4; ++g)
        acc[g] = MFMA16(bxr[g], a41, ZERO4);
      #pragma unroll
      for (int kc=0; kc<4; ++kc){
        half8 b = *(const half8*)(hrow + kc*32 + q*8);
        #pragma unroll
        for (int g=0; g<4; ++g)
          acc[g] = MFMA16(bfrag[g][kc], b, acc[g]);
      }
      #pragma unroll
      for (int rp=0; rp<2; ++rp){
        floatx2 yi = {acc[0][2*rp], acc[0][2*rp+1]};
        floatx2 yf = {acc[1][2*rp], acc[1][2*rp+1]};
        floatx2 yg = {acc[2][2*rp], acc[2][2*rp+1]};
        floatx2 yo = {acc[3][2*rp], acc[3][2*rp+1]};
        floatx2 h2 = lstm_cell2(yi, yf, yg, yo, c1[rp]);
        hv1[2*rp]   = (_Float16)h2[0];
        hv1[2*rp+1] = (_Float16)h2[1];
      }
      *(half4v*)&h_lds[(t+1)&1][cb+16][wv*16 + q*4] = hv1;
    }
    a40 = *(const half8*)a0p; a0p += astep;
    a41 = *(const half8*)a1p; a1p += astep;
    __syncthreads();
  }

  *(half4v*)&hout[(base + cb)*128      + wv*16 + q*4] = hv0;
  *(half4v*)&hout[(base + cb + 16)*128 + wv*16 + q*4] = hv1;
}

// ---------------------------------------------------------------------------
// Prep: conv/fusion weight layouts + conv2 background + decoder fold.
// ---------------------------------------------------------------------------
__global__ void prep_kernel(const float* __restrict__ w1, const float* __restrict__ b1,
                            const float* __restrict__ w2, const float* __restrict__ b2,
                            const float* __restrict__ fus_w,
                            const float* __restrict__ dec_wih, const float* __restrict__ dec_whh,
                            const float* __restrict__ dec_bih, const float* __restrict__ dec_bhh,
                            const float* __restrict__ out_w, const float* __restrict__ out_b,
                            _Float16* __restrict__ w1f, _Float16* __restrict__ w2f,
                            _Float16* __restrict__ fus_wf,
                            _Float16* __restrict__ whhp, float* __restrict__ biasp,
                            float* __restrict__ v2bg, float* __restrict__ bgmax)
{
  const int tid = threadIdx.x;
  const int gid = blockIdx.x*256 + tid;
  const int gstride = gridDim.x*256;
  for (int i = gid; i < 9*64*128; i += gstride){
    int s = i>>13, rem = i&8191, c1 = rem>>7, ci = rem&127;
    w1f[s*8448 + c1*132 + ci] = (_Float16)w1[c1*1152 + ci*9 + s];
  }
  for (int i = gid; i < 9*32*64; i += gstride){
    int s = i>>11, rem = i&2047, c2 = rem>>6, ci = rem&63;
    w2f[s*2176 + c2*68 + ci] = (_Float16)w2[c2*576 + ci*9 + s];
  }
  for (int i = gid; i < 128*160; i += gstride){
    int n = i/160, k = i%160;
    fus_wf[n*164 + k] = (_Float16)fus_w[i];
  }
  for (int i = gid; i < 512*128; i += gstride){
    int col = i>>7, k = i&127;
    float sc = ((col>>7)==2) ? L2E2 : L2E;
    float v = dec_whh[i] + dec_wih[col*2+0]*out_w[k] + dec_wih[col*2+1]*out_w[128+k];
    whhp[i] = (_Float16)(v*sc);
  }
  for (int i = gid; i < 512; i += gstride){
    float sc = ((i>>7)==2) ? L2E2 : L2E;
    biasp[i] = (dec_bih[i] + dec_bhh[i] + dec_wih[i*2+0]*out_b[0]
                + dec_wih[i*2+1]*out_b[1])*sc;
  }
  if (blockIdx.x == 0){
    __shared__ float S[288];
    __shared__ int bgm[32];
    for (int i=tid;i<288;i+=256){
      int c2=i/9, s=i%9;
      float a=0.f;
      for (int ci=0;ci<64;++ci) a += w2[c2*576+ci*9+s]*fmaxf(b1[ci],0.f);
      S[i]=a;
    }
    if (tid<32) bgm[tid]=0;
    __syncthreads();
    for (int i=tid;i<2048;i+=256){
      int cell=i>>5, c2=i&31, y=cell>>3, xx=cell&7;
      float a=b2[c2];
      for (int dy=0;dy<3;++dy){ int iy=y+dy-1; if((unsigned)iy>7u) continue;
        for (int dx=0;dx<3;++dx){ int ix=xx+dx-1; if((unsigned)ix>7u) continue;
          a += S[c2*9+dy*3+dx]; } }
      v2bg[cell*32+c2]=a;
      bool aff = (y<=2) || (y==3 && xx<=6) || (y>=4 && y<=6 && xx>=2 && xx<=6);
      if(!aff) atomicMax(&bgm[c2], __float_as_int(fmaxf(a,0.f)));
    }
    __syncthreads();
    if (tid<32) bgmax[tid]=__int_as_float(bgm[tid]);
  }
}

// ---------------------------------------------------------------------------
// Social pooling + sparse conv + maxpool + fusion — 512 threads / 8 waves
// (104 KB LDS, 16-batch tile). Work split: conv1 by (c1-slice = wv&3, cell
// parity = wv>>2); conv2 by oc&7==wv; fusion by n-tile = wv.
// ---------------------------------------------------------------------------
__global__ __launch_bounds__(512, 1) void social_fuse(
    const _Float16* __restrict__ h_enc, const _Float16* __restrict__ h_nb,
    const _Float16* __restrict__ w1f, const _Float16* __restrict__ w2f,
    const _Float16* __restrict__ fus_wf,
    const float* __restrict__ b1, const float* __restrict__ v2bg,
    const float* __restrict__ bgmax, const float* __restrict__ fus_b,
    float* __restrict__ fused)
{
  __shared__ __align__(16) _Float16 vecs[9*16*132];
  __shared__ __align__(16) _Float16 d1[27*16*68];
  __shared__ __align__(16) _Float16 A16[16*164];
  __shared__ int pooled[512];

  const int tid  = threadIdx.x;
  const int wv   = tid >> 6;
  const int lane = tid & 63;
  const int q    = lane >> 4;
  const int cb   = lane & 15;
  const long base = (long)blockIdx.x * 16;

  for (int i=tid; i<9*16*32; i+=512){
    int p = i>>9, rem = i&511, bb = rem>>5, j = rem&31;
    const _Float16* src = (p<8) ? (h_nb + (((base+bb))*8 + p)*128 + j*4)
                                : (h_enc + (base+bb)*128 + j*4);
    *(unsigned long long*)(vecs + p*2112 + bb*132 + j*4) = *(const unsigned long long*)src;
  }
  for (int i=tid; i<512; i+=512){
    int bb=i>>5, j=i&31;
    *(unsigned long long*)(A16 + bb*164 + j*4) =
        *(const unsigned long long*)(h_enc + (base+bb)*128 + j*4);
  }
  for (int i=tid; i<512; i+=512) pooled[i] = __float_as_int(bgmax[i&31]);
  __syncthreads();

  // ---- conv1: wave = (c1-slice wv&3, cell-parity wv>>2) ----
  {
    const int c1lane = (wv&3)*16 + cb;
    const int half   = wv >> 2;
    half8 bf1[9][4];
    #pragma unroll
    for (int s=0;s<9;++s)
      #pragma unroll
      for (int kc=0;kc<4;++kc)
        bf1[s][kc] = ld8(w1f + s*8448 + c1lane*132 + kc*32 + q*8);
    const float b1v = b1[c1lane];
    const float bg  = fmaxf(b1v, 0.f);

    #pragma unroll
    for (int ci=0; ci<27; ++ci){
      if ((ci & 1) != half) continue;
      const int y = DY[ci], x = DX[ci];
      floatx4 C = {0.f,0.f,0.f,0.f};
      #pragma unroll
      for (int p=0;p<9;++p){
        const int dy = PY[p]-y+1, dx = PX[p]-x+1;
        if (dy>=0 && dy<3 && dx>=0 && dx<3){
          const int s = dy*3+dx;
          const _Float16* ap = vecs + p*2112 + cb*132 + q*8;
          #pragma unroll
          for (int kc=0;kc<4;++kc)
            C = MFMA16(ld8(ap + kc*32), bf1[s][kc], C);
        }
      }
      _Float16* dp = d1 + ci*1088 + c1lane;
      #pragma unroll
      for (int r=0;r<4;++r)
        dp[(q*4+r)*68] = (_Float16)(fmaxf(b1v + C[r], 0.f) - bg);
    }
  }
  __syncthreads();

  // ---- conv2 + maxpool: out-cells split 8 ways ----
  {
    half8 bf2[9][2][2];
    #pragma unroll
    for (int s=0;s<9;++s)
      #pragma unroll
      for (int nt=0;nt<2;++nt)
        #pragma unroll
        for (int kc=0;kc<2;++kc)
          bf2[s][nt][kc] = ld8(w2f + s*2176 + (nt*16+cb)*68 + kc*32 + q*8);

    float rm0[4] = {0,0,0,0}, rm1[4] = {0,0,0,0};
    #pragma unroll
    for (int oc=0; oc<46; ++oc){
      if ((oc & 7) != wv) continue;
      const int y = OY[oc], x = OX[oc];
      const int cell = y*8+x;
      float v0 = v2bg[cell*32 + cb];
      float v1 = v2bg[cell*32 + 16 + cb];
      floatx4 C0 = {v0,v0,v0,v0}, C1 = {v1,v1,v1,v1};
      #pragma unroll
      for (int dy=0;dy<3;++dy)
        #pragma unroll
        for (int dx=0;dx<3;++dx){
          const int dc = d1idx(y+dy-1, x+dx-1);
          if (dc < 0) continue;
          const int s = dy*3+dx;
          const _Float16* ap = d1 + dc*1088 + cb*68 + q*8;
          #pragma unroll
          for (int kc=0;kc<2;++kc){
            half8 a = ld8(ap + kc*32);
            C0 = MFMA16(a, bf2[s][0][kc], C0);
            C1 = MFMA16(a, bf2[s][1][kc], C1);
          }
        }
      #pragma unroll
      for (int r=0;r<4;++r){
        rm0[r] = fmaxf(rm0[r], fmaxf(C0[r],0.f));
        rm1[r] = fmaxf(rm1[r], fmaxf(C1[r],0.f));
      }
    }
    #pragma unroll
    for (int r=0;r<4;++r){
      atomicMax(&pooled[(q*4+r)*32 + cb],      __float_as_int(rm0[r]));
      atomicMax(&pooled[(q*4+r)*32 + 16 + cb], __float_as_int(rm1[r]));
    }
  }
  __syncthreads();

  for (int i=tid;i<512;i+=512){
    int bb=i>>5, c2=i&31;
    A16[bb*164 + 128 + c2] = (_Float16)__int_as_float(pooled[i]);
  }
  __syncthreads();

  // ---- fusion: wave wv owns n-tile wv (16 outputs) ----
  {
    half8 bfF[5];
    #pragma unroll
    for (int kc=0;kc<5;++kc)
      bfF[kc] = ld8(fus_wf + (wv*16+cb)*164 + kc*32 + q*8);
    const float fb = fus_b[wv*16+cb];
    floatx4 C0 = {0.f,0.f,0.f,0.f};
    #pragma unroll
    for (int kc=0;kc<5;++kc){
      half8 a = ld8(A16 + cb*164 + kc*32 + q*8);
      C0 = MFMA16(a, bfF[kc], C0);
    }
    #pragma unroll
    for (int r=0;r<4;++r){
      const long row = base + q*4 + r;
      fused[row*128 + wv*16+cb] = tanh_raw(C0[r]+fb);
    }
  }
}

// ---------------------------------------------------------------------------
// Decoder with folded feedback (packed-pair cell, unchanged from R6).
// ---------------------------------------------------------------------------
__global__ __launch_bounds__(512, 4) void dec_mfma(
    const float* __restrict__ fused,
    const _Float16* __restrict__ whhp, const float* __restrict__ biasp,
    const float* __restrict__ w_ih,
    const float* __restrict__ out_w, const float* __restrict__ out_b,
    float* __restrict__ out)
{
  __shared__ _Float16 h_lds[2][16][136];
  __shared__ __align__(16) _Float16 wib[8][4][17][8];
  __shared__ float ow_lds[2][128];
  __shared__ float pred_lds[16][2];

  const int tid  = threadIdx.x;
  const int wv   = tid >> 6;
  const int lane = tid & 63;
  const int q    = lane >> 4;
  const int cb   = lane & 15;
  const long base = (long)blockIdx.x * 16;

  for (int i=tid;i<256;i+=512) ow_lds[i>>7][i&127] = out_w[i];
  for (int i=tid;i<2048;i+=512) h_lds[0][i>>7][i&127] = (_Float16)fused[base*128 + i];
  for (int i=tid;i<2048;i+=512) h_lds[1][i>>7][i&127] = (_Float16)0.f;

  if (q == 0){
    #pragma unroll
    for (int g=0; g<4; ++g){
      const float sc = (g==2) ? L2E2 : L2E;
      const int col = g*128 + wv*16 + cb;
      _Float16* d = &wib[wv][g][cb][0];
      d[0] = (_Float16)(-w_ih[col*2+0]*sc);
      d[1] = (_Float16)(-w_ih[col*2+1]*sc);
      #pragma unroll
      for (int j=2;j<8;++j) d[j] = (_Float16)0.f;
    }
  } else if (lane == 16){
    #pragma unroll
    for (int g=0; g<4; ++g){
      _Float16* d = &wib[wv][g][16][0];
      #pragma unroll
      for (int j=0;j<8;++j) d[j] = (_Float16)0.f;
    }
  }

  half8 bfrag[4][4];
  float bias_r[4][4];
  #pragma unroll
  for (int g=0; g<4; ++g){
    const int col = g*128 + wv*16 + cb;
    #pragma unroll
    for (int r=0; r<4; ++r) bias_r[g][r] = biasp[g*128 + wv*16 + q*4 + r];
    #pragma unroll
    for (int kc=0; kc<4; ++kc)
      bfrag[g][kc] = ld8(whhp + (long)col*128 + kc*32 + q*8);
  }
  float ob0 = out_b[0], ob1 = out_b[1];
  __syncthreads();

  {
    int pair = tid>>3, part = tid&7;
    if (pair < 32){
      int m = pair>>1, oc = pair&1;
      const float* owp = ow_lds[oc];
      float v = 0.f;
      #pragma unroll
      for (int k=part*16; k<part*16+16; ++k) v += owp[k]*(float)h_lds[0][m][k];
      v += __shfl_down(v, 4, 8);
      v += __shfl_down(v, 2, 8);
      v += __shfl_down(v, 1, 8);
      if (part==0) pred_lds[m][oc] = v + (oc ? ob1 : ob0);
    }
  }
  __syncthreads();

  const _Float16* wibp = &wib[wv][0][(q==0)?cb:16][0];
  floatx2 c_reg[2] = {{0,0},{0,0}};
  half4v hv;

  for (int t=0; t<25; ++t){
    const _Float16* hrow = &h_lds[t&1][cb][0];

    floatx4 acc[4];
    #pragma unroll
    for (int g=0; g<4; ++g)
      #pragma unroll
      for (int r=0; r<4; ++r) acc[g][r] = bias_r[g][r];

    if (t == 0){
      half8 pb = {0,0,0,0,0,0,0,0};
      if (q == 0){
        pb[0] = (_Float16)pred_lds[cb][0];
        pb[1] = (_Float16)pred_lds[cb][1];
      }
      #pragma unroll
      for (int g=0; g<4; ++g){
        half8 w = *(const half8*)(wibp + g*136);
        acc[g] = MFMA16(w, pb, acc[g]);
      }
    }
    #pragma unroll
    for (int kc=0; kc<4; ++kc){
      half8 b = *(const half8*)(hrow + kc*32 + q*8);
      #pragma unroll
      for (int g=0; g<4; ++g)
        acc[g] = MFMA16(bfrag[g][kc], b, acc[g]);
    }
    #pragma unroll
    for (int rp=0; rp<2; ++rp){
      floatx2 yi = {acc[0][2*rp], acc[0][2*rp+1]};
      floatx2 yf = {acc[1][2*rp], acc[1][2*rp+1]};
      floatx2 yg = {acc[2][2*rp], acc[2][2*rp+1]};
      floatx2 yo = {acc[3][2*rp], acc[3][2*rp+1]};
      floatx2 h2 = lstm_cell2(yi, yf, yg, yo, c_reg[rp]);
      hv[2*rp]   = (_Float16)h2[0];
      hv[2*rp+1] = (_Float16)h2[1];
    }
    _Float16 (*hw)[136] = h_lds[(t+1)&1];
    *(half4v*)&hw[cb][wv*16 + q*4] = hv;
    __syncthreads();
    {
      int pair = tid>>3, part = tid&7;
      if (pair < 32){
        int m = pair>>1, oc = pair&1;
        const float* owp = ow_lds[oc];
        float v = 0.f;
        #pragma unroll
        for (int k=part*16; k<part*16+16; ++k) v += owp[k]*(float)hw[m][k];
        v += __shfl_down(v, 4, 8);
        v += __shfl_down(v, 2, 8);
        v += __shfl_down(v, 1, 8);
        if (part==0)
          out[(base+m)*50 + t*2 + oc] = v + (oc ? ob1 : ob0);
      }
    }
  }
}

// ---------------------------------------------------------------------------
extern "C" void kernel_launch(void* const* d_in, const int* in_sizes, int n_in,
                              void* d_out, int out_size, void* d_ws, size_t ws_size,
                              hipStream_t stream)
{
  (void)in_sizes; (void)n_in; (void)out_size; (void)ws_size;
  const float* target   = (const float*)d_in[0];
  const float* neigh    = (const float*)d_in[1];
  const float* enc_w_ih = (const float*)d_in[4];
  const float* enc_w_hh = (const float*)d_in[5];
  const float* enc_b_ih = (const float*)d_in[6];
  const float* enc_b_hh = (const float*)d_in[7];
  const float* nb_w_ih  = (const float*)d_in[8];
  const float* nb_w_hh  = (const float*)d_in[9];
  const float* nb_b_ih  = (const float*)d_in[10];
  const float* nb_b_hh  = (const float*)d_in[11];
  const float* w1       = (const float*)d_in[12];
  const float* b1       = (const float*)d_in[13];
  const float* w2       = (const float*)d_in[14];
  const float* b2       = (const float*)d_in[15];
  const float* fus_w    = (const float*)d_in[16];
  const float* fus_b    = (const float*)d_in[17];
  const float* dec_w_ih = (const float*)d_in[18];
  const float* dec_w_hh = (const float*)d_in[19];
  const float* dec_b_ih = (const float*)d_in[20];
  const float* dec_b_hh = (const float*)d_in[21];
  const float* out_w    = (const float*)d_in[22];
  const float* out_b    = (const float*)d_in[23];

  char* ws = (char*)d_ws;
  _Float16* h_nb16  = (_Float16*)ws;                       // 16 MB
  _Float16* h_enc16 = (_Float16*)(ws + (16u<<20));         // 2 MB
  float*    fusedp  = (float*)(ws + (18u<<20));            // 4 MB
  char* aux = ws + (22u<<20);
  _Float16* w1f    = (_Float16*)aux;                       // 152,064 B
  _Float16* w2f    = (_Float16*)(aux + 152064);            // 39,168 B
  _Float16* fus_wf = (_Float16*)(aux + 152064 + 39168);    // 41,984 B
  float*    v2bg   = (float*)(aux + 233216);               // 8,192 B
  float*    bgmaxp = (float*)(aux + 241408);               // 128 B
  _Float16* whhp   = (_Float16*)(aux + 241536);            // 131,072 B
  float*    biasp  = (float*)(aux + 241536 + 131072);      // 2,048 B

  prep_kernel<<<64, 256, 0, stream>>>(w1, b1, w2, b2, fus_w,
                                      dec_w_ih, dec_w_hh, dec_b_ih, dec_b_hh,
                                      out_w, out_b,
                                      w1f, w2f, fus_wf, whhp, biasp, v2bg, bgmaxp);
  lstm_all<<<2304, 512, 0, stream>>>(target, neigh,
                                     enc_w_ih, enc_w_hh, enc_b_ih, enc_b_hh,
                                     nb_w_ih, nb_w_hh, nb_b_ih, nb_b_hh,
                                     h_enc16, h_nb16);
  social_fuse<<<512, 512, 0, stream>>>(h_enc16, h_nb16, w1f, w2f, fus_wf,
                                       b1, v2bg, bgmaxp, fus_b, fusedp);
  dec_mfma<<<512, 512, 0, stream>>>(fusedp, whhp, biasp, dec_w_ih,
                                    out_w, out_b, (float*)d_out);
}

// Round 8
// 478.652 us; speedup vs baseline: 1.0047x; 1.0047x over previous
//
#include <hip/hip_runtime.h>

typedef _Float16 half8  __attribute__((ext_vector_type(8)));
typedef _Float16 half4v __attribute__((ext_vector_type(4)));
typedef float  floatx4  __attribute__((ext_vector_type(4)));
typedef float  floatx2  __attribute__((ext_vector_type(2)));

#define MFMA16(A,B,C) __builtin_amdgcn_mfma_f32_16x16x32_f16((A),(B),(C),0,0,0)

#define L2E  1.4426950408889634f
#define L2E2 2.8853900817779268f

__device__ __forceinline__ float rcpf(float x){ return __builtin_amdgcn_rcpf(x); }
__device__ __forceinline__ float ex2(float x){ return __builtin_amdgcn_exp2f(x); }
__device__ __forceinline__ float tanh_raw(float c){
  return 1.0f - 2.0f*rcpf(1.0f + ex2(L2E2*c));
}
__device__ __forceinline__ half8 ld8(const _Float16* p){
  half4v a = *(const half4v*)p;
  half4v b = *(const half4v*)(p+4);
  return __builtin_shufflevector(a,b,0,1,2,3,4,5,6,7);
}

__device__ __forceinline__ floatx2 ex2v(floatx2 x){
  floatx2 r; r[0]=ex2(x[0]); r[1]=ex2(x[1]); return r;
}
__device__ __forceinline__ floatx2 rcpv(floatx2 x){
  floatx2 r; r[0]=rcpf(x[0]); r[1]=rcpf(x[1]); return r;
}

// Fused LSTM cell on a PAIR of cells (float2 ext-vector -> VOP3P
// v_pk_{add,mul,fma}_f32 for the non-trans arithmetic).
// 7 trans/cell (5 ex2 + 2 rcp), exact algebra:
//   c' = (c*P + (C-1)*Q) * rcp(P*Q),  h = (E-1)/((1+F)(1+E))
// with A=2^-yi B=2^-yf C=2^yg F=2^-yo E=2^(2L c'), P=(1+A)(1+C), Q=1+B.
__device__ __forceinline__ floatx2 lstm_cell2(floatx2 yi, floatx2 yf,
                                              floatx2 yg, floatx2 yo,
                                              floatx2& c){
  floatx2 A = ex2v(-yi), B = ex2v(-yf), C = ex2v(yg);
  const floatx2 one = {1.f, 1.f};
  floatx2 P = (one + A)*(one + C);
  floatx2 Q = one + B;
  floatx2 r = rcpv(P*Q);
  floatx2 cn = (c*P + (C - one)*Q)*r;
  c = cn;
  floatx2 F = ex2v(-yo), E = ex2v(L2E2*cn);
  floatx2 r3 = rcpv((one + F)*(one + E));
  return (E - one)*r3;
}

// grid geometry tables (compile-time foldable)
static __device__ constexpr int DY[27] = {0,0,0,0,0,0,0,0, 1,1,1,1,1,1,1,1, 2,2, 3,3,3,4,4,4,5,5,5};
static __device__ constexpr int DX[27] = {0,1,2,3,4,5,6,7, 0,1,2,3,4,5,6,7, 0,1, 3,4,5,3,4,5,3,4,5};
static __device__ constexpr int PY[9]  = {0,0,0,0,0,0,0,1,4};
static __device__ constexpr int PX[9]  = {1,2,3,4,5,6,7,0,4};
static __device__ constexpr int OY[46] = {0,0,0,0,0,0,0,0, 1,1,1,1,1,1,1,1, 2,2,2,2,2,2,2,2,
                                          3,3,3,3,3,3,3, 4,4,4,4,4, 5,5,5,5,5, 6,6,6,6,6};
static __device__ constexpr int OX[46] = {0,1,2,3,4,5,6,7, 0,1,2,3,4,5,6,7, 0,1,2,3,4,5,6,7,
                                          0,1,2,3,4,5,6, 2,3,4,5,6, 2,3,4,5,6, 2,3,4,5,6};
__device__ constexpr int d1idx(int iy,int ix){
  return (iy<0||iy>7||ix<0||ix>7) ? -1 :
         (iy<=1) ? iy*8+ix :
         (iy==2 && ix<=1) ? 16+ix :
         (iy>=3 && iy<=5 && ix>=3 && ix<=5) ? 18+(iy-3)*3+(ix-3) : -1;
}

// ---------------------------------------------------------------------------
// Combined encoder: batch-32 per block (two sequential 16-batch subtiles
// sharing ONE barrier per timestep), packed-pair cell, bxr register hoist.
// Frozen since R7 (at structural issue floor: VALU+MFMA ~94%, 7-trans cell,
// scheduling interventions proven null).
// ---------------------------------------------------------------------------
__global__ __launch_bounds__(512, 4) void lstm_all(
    const float* __restrict__ target, const float* __restrict__ neigh,
    const float* __restrict__ e_wih, const float* __restrict__ e_whh,
    const float* __restrict__ e_bih, const float* __restrict__ e_bhh,
    const float* __restrict__ n_wih, const float* __restrict__ n_whh,
    const float* __restrict__ n_bih, const float* __restrict__ n_bhh,
    _Float16* __restrict__ h_enc16, _Float16* __restrict__ h_nb16)
{
  __shared__ _Float16 h_lds[2][32][136];
  __shared__ _Float16 xf16[32][168];
  __shared__ __align__(16) _Float16 wihb[8][4][17][8];

  const int tid  = threadIdx.x;
  const int wv   = tid >> 6;
  const int lane = tid & 63;
  const int q    = lane >> 4;
  const int cb   = lane & 15;

  const bool enc = (blockIdx.x < 256);
  const float* x   = enc ? target : neigh;
  const float* wih = enc ? e_wih : n_wih;
  const float* whh = enc ? e_whh : n_whh;
  const float* bih = enc ? e_bih : n_bih;
  const float* bhh = enc ? e_bhh : n_bhh;
  _Float16* hout   = enc ? h_enc16 : h_nb16;
  const long base  = enc ? (long)blockIdx.x*32 : (long)(blockIdx.x-256)*32;

  for (int i = tid; i < 32*168; i += 512){
    int seq = i/168, rem = i%168, t = rem>>3, f = rem&7;
    float v = 0.f;
    if (t < 20) v = (f < 7) ? x[base*140 + seq*140 + t*7 + f] : 1.0f;
    xf16[seq][rem] = (_Float16)v;
  }
  for (int i = tid; i < 32*136; i += 512) ((_Float16*)h_lds)[i] = (_Float16)0.f;

  if (q == 0){
    #pragma unroll
    for (int g=0; g<4; ++g){
      const float sc = (g==2) ? L2E2 : L2E;
      const int col = g*128 + wv*16 + cb;
      _Float16* d = &wihb[wv][g][cb][0];
      #pragma unroll
      for (int j=0;j<7;++j) d[j] = (_Float16)(wih[col*7+j]*sc);
      d[7] = (_Float16)((bih[col]+bhh[col])*sc);
    }
  } else if (lane == 16){
    #pragma unroll
    for (int g=0; g<4; ++g){
      _Float16* d = &wihb[wv][g][16][0];
      #pragma unroll
      for (int j=0;j<8;++j) d[j] = (_Float16)0.f;
    }
  }

  half8 bfrag[4][4];
  #pragma unroll
  for (int g=0; g<4; ++g){
    const float sc = (g==2) ? L2E2 : L2E;
    const int col = g*128 + wv*16 + cb;
    #pragma unroll
    for (int kc=0; kc<4; ++kc){
      const float* src = whh + (long)col*128 + kc*32 + q*8;
      half8 f;
      #pragma unroll
      for (int j=0;j<8;++j) f[j] = (_Float16)(src[j]*sc);
      bfrag[g][kc] = f;
    }
  }
  __syncthreads();

  const _Float16* bxp = &wihb[wv][0][(q==0)?cb:16][0];
  const _Float16* zsrc = &wihb[wv][0][16][0];
  const _Float16* a0p = (q==0) ? &xf16[cb][0]    : zsrc;
  const _Float16* a1p = (q==0) ? &xf16[cb+16][0] : zsrc;
  const int astep = (q==0) ? 8 : 0;
  half8 a40 = *(const half8*)a0p; a0p += astep;
  half8 a41 = *(const half8*)a1p; a1p += astep;

  half8 bxr[4];
  #pragma unroll
  for (int g=0; g<4; ++g) bxr[g] = *(const half8*)(bxp + g*136);

  floatx2 c0[2] = {{0,0},{0,0}}, c1[2] = {{0,0},{0,0}};
  half4v hv0 = {0,0,0,0}, hv1 = {0,0,0,0};
  const floatx4 ZERO4 = {0.f,0.f,0.f,0.f};

  for (int t=0; t<20; ++t){
    // ---- subtile 0 (batch rows cb) ----
    {
      const _Float16* hrow = &h_lds[t&1][cb][0];
      floatx4 acc[4];
      #pragma unroll
      for (int g=0; g<4; ++g)
        acc[g] = MFMA16(bxr[g], a40, ZERO4);
      #pragma unroll
      for (int kc=0; kc<4; ++kc){
        half8 b = *(const half8*)(hrow + kc*32 + q*8);
        #pragma unroll
        for (int g=0; g<4; ++g)
          acc[g] = MFMA16(bfrag[g][kc], b, acc[g]);
      }
      #pragma unroll
      for (int rp=0; rp<2; ++rp){
        floatx2 yi = {acc[0][2*rp], acc[0][2*rp+1]};
        floatx2 yf = {acc[1][2*rp], acc[1][2*rp+1]};
        floatx2 yg = {acc[2][2*rp], acc[2][2*rp+1]};
        floatx2 yo = {acc[3][2*rp], acc[3][2*rp+1]};
        floatx2 h2 = lstm_cell2(yi, yf, yg, yo, c0[rp]);
        hv0[2*rp]   = (_Float16)h2[0];
        hv0[2*rp+1] = (_Float16)h2[1];
      }
      *(half4v*)&h_lds[(t+1)&1][cb][wv*16 + q*4] = hv0;
    }
    // ---- subtile 1 (batch rows cb+16) ----
    {
      const _Float16* hrow = &h_lds[t&1][cb+16][0];
      floatx4 acc[4];
      #pragma unroll
      for (int g=0; g<4; ++g)
        acc[g] = MFMA16(bxr[g], a41, ZERO4);
      #pragma unroll
      for (int kc=0; kc<4; ++kc){
        half8 b = *(const half8*)(hrow + kc*32 + q*8);
        #pragma unroll
        for (int g=0; g<4; ++g)
          acc[g] = MFMA16(bfrag[g][kc], b, acc[g]);
      }
      #pragma unroll
      for (int rp=0; rp<2; ++rp){
        floatx2 yi = {acc[0][2*rp], acc[0][2*rp+1]};
        floatx2 yf = {acc[1][2*rp], acc[1][2*rp+1]};
        floatx2 yg = {acc[2][2*rp], acc[2][2*rp+1]};
        floatx2 yo = {acc[3][2*rp], acc[3][2*rp+1]};
        floatx2 h2 = lstm_cell2(yi, yf, yg, yo, c1[rp]);
        hv1[2*rp]   = (_Float16)h2[0];
        hv1[2*rp+1] = (_Float16)h2[1];
      }
      *(half4v*)&h_lds[(t+1)&1][cb+16][wv*16 + q*4] = hv1;
    }
    a40 = *(const half8*)a0p; a0p += astep;
    a41 = *(const half8*)a1p; a1p += astep;
    __syncthreads();
  }

  *(half4v*)&hout[(base + cb)*128      + wv*16 + q*4] = hv0;
  *(half4v*)&hout[(base + cb + 16)*128 + wv*16 + q*4] = hv1;
}

// ---------------------------------------------------------------------------
// Prep: conv/fusion weight layouts + conv2 background + decoder fold.
// ---------------------------------------------------------------------------
__global__ void prep_kernel(const float* __restrict__ w1, const float* __restrict__ b1,
                            const float* __restrict__ w2, const float* __restrict__ b2,
                            const float* __restrict__ fus_w,
                            const float* __restrict__ dec_wih, const float* __restrict__ dec_whh,
                            const float* __restrict__ dec_bih, const float* __restrict__ dec_bhh,
                            const float* __restrict__ out_w, const float* __restrict__ out_b,
                            _Float16* __restrict__ w1f, _Float16* __restrict__ w2f,
                            _Float16* __restrict__ fus_wf,
                            _Float16* __restrict__ whhp, float* __restrict__ biasp,
                            float* __restrict__ v2bg, float* __restrict__ bgmax)
{
  const int tid = threadIdx.x;
  const int gid = blockIdx.x*256 + tid;
  const int gstride = gridDim.x*256;
  for (int i = gid; i < 9*64*128; i += gstride){
    int s = i>>13, rem = i&8191, c1 = rem>>7, ci = rem&127;
    w1f[s*8448 + c1*132 + ci] = (_Float16)w1[c1*1152 + ci*9 + s];
  }
  for (int i = gid; i < 9*32*64; i += gstride){
    int s = i>>11, rem = i&2047, c2 = rem>>6, ci = rem&63;
    w2f[s*2176 + c2*68 + ci] = (_Float16)w2[c2*576 + ci*9 + s];
  }
  for (int i = gid; i < 128*160; i += gstride){
    int n = i/160, k = i%160;
    fus_wf[n*164 + k] = (_Float16)fus_w[i];
  }
  for (int i = gid; i < 512*128; i += gstride){
    int col = i>>7, k = i&127;
    float sc = ((col>>7)==2) ? L2E2 : L2E;
    float v = dec_whh[i] + dec_wih[col*2+0]*out_w[k] + dec_wih[col*2+1]*out_w[128+k];
    whhp[i] = (_Float16)(v*sc);
  }
  for (int i = gid; i < 512; i += gstride){
    float sc = ((i>>7)==2) ? L2E2 : L2E;
    biasp[i] = (dec_bih[i] + dec_bhh[i] + dec_wih[i*2+0]*out_b[0]
                + dec_wih[i*2+1]*out_b[1])*sc;
  }
  if (blockIdx.x == 0){
    __shared__ float S[288];
    __shared__ int bgm[32];
    for (int i=tid;i<288;i+=256){
      int c2=i/9, s=i%9;
      float a=0.f;
      for (int ci=0;ci<64;++ci) a += w2[c2*576+ci*9+s]*fmaxf(b1[ci],0.f);
      S[i]=a;
    }
    if (tid<32) bgm[tid]=0;
    __syncthreads();
    for (int i=tid;i<2048;i+=256){
      int cell=i>>5, c2=i&31, y=cell>>3, xx=cell&7;
      float a=b2[c2];
      for (int dy=0;dy<3;++dy){ int iy=y+dy-1; if((unsigned)iy>7u) continue;
        for (int dx=0;dx<3;++dx){ int ix=xx+dx-1; if((unsigned)ix>7u) continue;
          a += S[c2*9+dy*3+dx]; } }
      v2bg[cell*32+c2]=a;
      bool aff = (y<=2) || (y==3 && xx<=6) || (y>=4 && y<=6 && xx>=2 && xx<=6);
      if(!aff) atomicMax(&bgm[c2], __float_as_int(fmaxf(a,0.f)));
    }
    __syncthreads();
    if (tid<32) bgmax[tid]=__int_as_float(bgm[tid]);
  }
}

// ---------------------------------------------------------------------------
// Social pooling + sparse conv + maxpool + fusion — 512 threads / 8 waves
// (104 KB LDS, 16-batch tile). Work split: conv1 by (c1-slice = wv&3, cell
// parity = wv>>2); conv2 by oc&7==wv; fusion by n-tile = wv.
// ---------------------------------------------------------------------------
__global__ __launch_bounds__(512, 1) void social_fuse(
    const _Float16* __restrict__ h_enc, const _Float16* __restrict__ h_nb,
    const _Float16* __restrict__ w1f, const _Float16* __restrict__ w2f,
    const _Float16* __restrict__ fus_wf,
    const float* __restrict__ b1, const float* __restrict__ v2bg,
    const float* __restrict__ bgmax, const float* __restrict__ fus_b,
    float* __restrict__ fused)
{
  __shared__ __align__(16) _Float16 vecs[9*16*132];
  __shared__ __align__(16) _Float16 d1[27*16*68];
  __shared__ __align__(16) _Float16 A16[16*164];
  __shared__ int pooled[512];

  const int tid  = threadIdx.x;
  const int wv   = tid >> 6;
  const int lane = tid & 63;
  const int q    = lane >> 4;
  const int cb   = lane & 15;
  const long base = (long)blockIdx.x * 16;

  for (int i=tid; i<9*16*32; i+=512){
    int p = i>>9, rem = i&511, bb = rem>>5, j = rem&31;
    const _Float16* src = (p<8) ? (h_nb + (((base+bb))*8 + p)*128 + j*4)
                                : (h_enc + (base+bb)*128 + j*4);
    *(unsigned long long*)(vecs + p*2112 + bb*132 + j*4) = *(const unsigned long long*)src;
  }
  for (int i=tid; i<512; i+=512){
    int bb=i>>5, j=i&31;
    *(unsigned long long*)(A16 + bb*164 + j*4) =
        *(const unsigned long long*)(h_enc + (base+bb)*128 + j*4);
  }
  for (int i=tid; i<512; i+=512) pooled[i] = __float_as_int(bgmax[i&31]);
  __syncthreads();

  // ---- conv1: wave = (c1-slice wv&3, cell-parity wv>>2) ----
  {
    const int c1lane = (wv&3)*16 + cb;
    const int half   = wv >> 2;
    half8 bf1[9][4];
    #pragma unroll
    for (int s=0;s<9;++s)
      #pragma unroll
      for (int kc=0;kc<4;++kc)
        bf1[s][kc] = ld8(w1f + s*8448 + c1lane*132 + kc*32 + q*8);
    const float b1v = b1[c1lane];
    const float bg  = fmaxf(b1v, 0.f);

    #pragma unroll
    for (int ci=0; ci<27; ++ci){
      if ((ci & 1) != half) continue;
      const int y = DY[ci], x = DX[ci];
      floatx4 C = {0.f,0.f,0.f,0.f};
      #pragma unroll
      for (int p=0;p<9;++p){
        const int dy = PY[p]-y+1, dx = PX[p]-x+1;
        if (dy>=0 && dy<3 && dx>=0 && dx<3){
          const int s = dy*3+dx;
          const _Float16* ap = vecs + p*2112 + cb*132 + q*8;
          #pragma unroll
          for (int kc=0;kc<4;++kc)
            C = MFMA16(ld8(ap + kc*32), bf1[s][kc], C);
        }
      }
      _Float16* dp = d1 + ci*1088 + c1lane;
      #pragma unroll
      for (int r=0;r<4;++r)
        dp[(q*4+r)*68] = (_Float16)(fmaxf(b1v + C[r], 0.f) - bg);
    }
  }
  __syncthreads();

  // ---- conv2 + maxpool: out-cells split 8 ways ----
  {
    half8 bf2[9][2][2];
    #pragma unroll
    for (int s=0;s<9;++s)
      #pragma unroll
      for (int nt=0;nt<2;++nt)
        #pragma unroll
        for (int kc=0;kc<2;++kc)
          bf2[s][nt][kc] = ld8(w2f + s*2176 + (nt*16+cb)*68 + kc*32 + q*8);

    float rm0[4] = {0,0,0,0}, rm1[4] = {0,0,0,0};
    #pragma unroll
    for (int oc=0; oc<46; ++oc){
      if ((oc & 7) != wv) continue;
      const int y = OY[oc], x = OX[oc];
      const int cell = y*8+x;
      float v0 = v2bg[cell*32 + cb];
      float v1 = v2bg[cell*32 + 16 + cb];
      floatx4 C0 = {v0,v0,v0,v0}, C1 = {v1,v1,v1,v1};
      #pragma unroll
      for (int dy=0;dy<3;++dy)
        #pragma unroll
        for (int dx=0;dx<3;++dx){
          const int dc = d1idx(y+dy-1, x+dx-1);
          if (dc < 0) continue;
          const int s = dy*3+dx;
          const _Float16* ap = d1 + dc*1088 + cb*68 + q*8;
          #pragma unroll
          for (int kc=0;kc<2;++kc){
            half8 a = ld8(ap + kc*32);
            C0 = MFMA16(a, bf2[s][0][kc], C0);
            C1 = MFMA16(a, bf2[s][1][kc], C1);
          }
        }
      #pragma unroll
      for (int r=0;r<4;++r){
        rm0[r] = fmaxf(rm0[r], fmaxf(C0[r],0.f));
        rm1[r] = fmaxf(rm1[r], fmaxf(C1[r],0.f));
      }
    }
    #pragma unroll
    for (int r=0;r<4;++r){
      atomicMax(&pooled[(q*4+r)*32 + cb],      __float_as_int(rm0[r]));
      atomicMax(&pooled[(q*4+r)*32 + 16 + cb], __float_as_int(rm1[r]));
    }
  }
  __syncthreads();

  for (int i=tid;i<512;i+=512){
    int bb=i>>5, c2=i&31;
    A16[bb*164 + 128 + c2] = (_Float16)__int_as_float(pooled[i]);
  }
  __syncthreads();

  // ---- fusion: wave wv owns n-tile wv (16 outputs) ----
  {
    half8 bfF[5];
    #pragma unroll
    for (int kc=0;kc<5;++kc)
      bfF[kc] = ld8(fus_wf + (wv*16+cb)*164 + kc*32 + q*8);
    const float fb = fus_b[wv*16+cb];
    floatx4 C0 = {0.f,0.f,0.f,0.f};
    #pragma unroll
    for (int kc=0;kc<5;++kc){
      half8 a = ld8(A16 + cb*164 + kc*32 + q*8);
      C0 = MFMA16(a, bfF[kc], C0);
    }
    #pragma unroll
    for (int r=0;r<4;++r){
      const long row = base + q*4 + r;
      fused[row*128 + wv*16+cb] = tanh_raw(C0[r]+fb);
    }
  }
}

// ---------------------------------------------------------------------------
// Decoder with folded feedback. R8: batch-32 per block (256 blocks), two
// sequential subtiles sharing one barrier per step — mirrors the lstm_all
// R2 transform. All 512 threads now carry the output projection (64 pairs
// × 8 partials). h_lds[1] zero-init dropped (fully written at t=0).
// ---------------------------------------------------------------------------
__global__ __launch_bounds__(512, 4) void dec_mfma(
    const float* __restrict__ fused,
    const _Float16* __restrict__ whhp, const float* __restrict__ biasp,
    const float* __restrict__ w_ih,
    const float* __restrict__ out_w, const float* __restrict__ out_b,
    float* __restrict__ out)
{
  __shared__ _Float16 h_lds[2][32][136];
  __shared__ __align__(16) _Float16 wib[8][4][17][8];
  __shared__ float ow_lds[2][128];
  __shared__ float pred_lds[32][2];

  const int tid  = threadIdx.x;
  const int wv   = tid >> 6;
  const int lane = tid & 63;
  const int q    = lane >> 4;
  const int cb   = lane & 15;
  const long base = (long)blockIdx.x * 32;

  for (int i=tid;i<256;i+=512) ow_lds[i>>7][i&127] = out_w[i];
  for (int i=tid;i<4096;i+=512) h_lds[0][i>>7][i&127] = (_Float16)fused[base*128 + i];

  if (q == 0){
    #pragma unroll
    for (int g=0; g<4; ++g){
      const float sc = (g==2) ? L2E2 : L2E;
      const int col = g*128 + wv*16 + cb;
      _Float16* d = &wib[wv][g][cb][0];
      d[0] = (_Float16)(-w_ih[col*2+0]*sc);
      d[1] = (_Float16)(-w_ih[col*2+1]*sc);
      #pragma unroll
      for (int j=2;j<8;++j) d[j] = (_Float16)0.f;
    }
  } else if (lane == 16){
    #pragma unroll
    for (int g=0; g<4; ++g){
      _Float16* d = &wib[wv][g][16][0];
      #pragma unroll
      for (int j=0;j<8;++j) d[j] = (_Float16)0.f;
    }
  }

  half8 bfrag[4][4];
  float bias_r[4][4];
  #pragma unroll
  for (int g=0; g<4; ++g){
    const int col = g*128 + wv*16 + cb;
    #pragma unroll
    for (int r=0; r<4; ++r) bias_r[g][r] = biasp[g*128 + wv*16 + q*4 + r];
    #pragma unroll
    for (int kc=0; kc<4; ++kc)
      bfrag[g][kc] = ld8(whhp + (long)col*128 + kc*32 + q*8);
  }
  float ob0 = out_b[0], ob1 = out_b[1];
  __syncthreads();

  {
    int pair = tid>>3, part = tid&7;       // 64 pairs: m=0..31, oc=0..1
    int m = pair>>1, oc = pair&1;
    const float* owp = ow_lds[oc];
    float v = 0.f;
    #pragma unroll
    for (int k=part*16; k<part*16+16; ++k) v += owp[k]*(float)h_lds[0][m][k];
    v += __shfl_down(v, 4, 8);
    v += __shfl_down(v, 2, 8);
    v += __shfl_down(v, 1, 8);
    if (part==0) pred_lds[m][oc] = v + (oc ? ob1 : ob0);
  }
  __syncthreads();

  const _Float16* wibp = &wib[wv][0][(q==0)?cb:16][0];
  floatx2 c0[2] = {{0,0},{0,0}}, c1[2] = {{0,0},{0,0}};
  half4v hv0, hv1;

  for (int t=0; t<25; ++t){
    // ---- subtile 0 (batch rows cb) ----
    {
      const _Float16* hrow = &h_lds[t&1][cb][0];
      floatx4 acc[4];
      #pragma unroll
      for (int g=0; g<4; ++g)
        #pragma unroll
        for (int r=0; r<4; ++r) acc[g][r] = bias_r[g][r];
      if (t == 0){
        half8 pb = {0,0,0,0,0,0,0,0};
        if (q == 0){
          pb[0] = (_Float16)pred_lds[cb][0];
          pb[1] = (_Float16)pred_lds[cb][1];
        }
        #pragma unroll
        for (int g=0; g<4; ++g){
          half8 w = *(const half8*)(wibp + g*136);
          acc[g] = MFMA16(w, pb, acc[g]);
        }
      }
      #pragma unroll
      for (int kc=0; kc<4; ++kc){
        half8 b = *(const half8*)(hrow + kc*32 + q*8);
        #pragma unroll
        for (int g=0; g<4; ++g)
          acc[g] = MFMA16(bfrag[g][kc], b, acc[g]);
      }
      #pragma unroll
      for (int rp=0; rp<2; ++rp){
        floatx2 yi = {acc[0][2*rp], acc[0][2*rp+1]};
        floatx2 yf = {acc[1][2*rp], acc[1][2*rp+1]};
        floatx2 yg = {acc[2][2*rp], acc[2][2*rp+1]};
        floatx2 yo = {acc[3][2*rp], acc[3][2*rp+1]};
        floatx2 h2 = lstm_cell2(yi, yf, yg, yo, c0[rp]);
        hv0[2*rp]   = (_Float16)h2[0];
        hv0[2*rp+1] = (_Float16)h2[1];
      }
      *(half4v*)&h_lds[(t+1)&1][cb][wv*16 + q*4] = hv0;
    }
    // ---- subtile 1 (batch rows cb+16) ----
    {
      const _Float16* hrow = &h_lds[t&1][cb+16][0];
      floatx4 acc[4];
      #pragma unroll
      for (int g=0; g<4; ++g)
        #pragma unroll
        for (int r=0; r<4; ++r) acc[g][r] = bias_r[g][r];
      if (t == 0){
        half8 pb = {0,0,0,0,0,0,0,0};
        if (q == 0){
          pb[0] = (_Float16)pred_lds[cb+16][0];
          pb[1] = (_Float16)pred_lds[cb+16][1];
        }
        #pragma unroll
        for (int g=0; g<4; ++g){
          half8 w = *(const half8*)(wibp + g*136);
          acc[g] = MFMA16(w, pb, acc[g]);
        }
      }
      #pragma unroll
      for (int kc=0; kc<4; ++kc){
        half8 b = *(const half8*)(hrow + kc*32 + q*8);
        #pragma unroll
        for (int g=0; g<4; ++g)
          acc[g] = MFMA16(bfrag[g][kc], b, acc[g]);
      }
      #pragma unroll
      for (int rp=0; rp<2; ++rp){
        floatx2 yi = {acc[0][2*rp], acc[0][2*rp+1]};
        floatx2 yf = {acc[1][2*rp], acc[1][2*rp+1]};
        floatx2 yg = {acc[2][2*rp], acc[2][2*rp+1]};
        floatx2 yo = {acc[3][2*rp], acc[3][2*rp+1]};
        floatx2 h2 = lstm_cell2(yi, yf, yg, yo, c1[rp]);
        hv1[2*rp]   = (_Float16)h2[0];
        hv1[2*rp+1] = (_Float16)h2[1];
      }
      *(half4v*)&h_lds[(t+1)&1][cb+16][wv*16 + q*4] = hv1;
    }
    __syncthreads();
    {
      _Float16 (*hw)[136] = h_lds[(t+1)&1];
      int pair = tid>>3, part = tid&7;     // 64 pairs: m=0..31, oc=0..1
      int m = pair>>1, oc = pair&1;
      const float* owp = ow_lds[oc];
      float v = 0.f;
      #pragma unroll
      for (int k=part*16; k<part*16+16; ++k) v += owp[k]*(float)hw[m][k];
      v += __shfl_down(v, 4, 8);
      v += __shfl_down(v, 2, 8);
      v += __shfl_down(v, 1, 8);
      if (part==0)
        out[(base+m)*50 + t*2 + oc] = v + (oc ? ob1 : ob0);
    }
  }
}

// ---------------------------------------------------------------------------
extern "C" void kernel_launch(void* const* d_in, const int* in_sizes, int n_in,
                              void* d_out, int out_size, void* d_ws, size_t ws_size,
                              hipStream_t stream)
{
  (void)in_sizes; (void)n_in; (void)out_size; (void)ws_size;
  const float* target   = (const float*)d_in[0];
  const float* neigh    = (const float*)d_in[1];
  const float* enc_w_ih = (const float*)d_in[4];
  const float* enc_w_hh = (const float*)d_in[5];
  const float* enc_b_ih = (const float*)d_in[6];
  const float* enc_b_hh = (const float*)d_in[7];
  const float* nb_w_ih  = (const float*)d_in[8];
  const float* nb_w_hh  = (const float*)d_in[9];
  const float* nb_b_ih  = (const float*)d_in[10];
  const float* nb_b_hh  = (const float*)d_in[11];
  const float* w1       = (const float*)d_in[12];
  const float* b1       = (const float*)d_in[13];
  const float* w2       = (const float*)d_in[14];
  const float* b2       = (const float*)d_in[15];
  const float* fus_w    = (const float*)d_in[16];
  const float* fus_b    = (const float*)d_in[17];
  const float* dec_w_ih = (const float*)d_in[18];
  const float* dec_w_hh = (const float*)d_in[19];
  const float* dec_b_ih = (const float*)d_in[20];
  const float* dec_b_hh = (const float*)d_in[21];
  const float* out_w    = (const float*)d_in[22];
  const float* out_b    = (const float*)d_in[23];

  char* ws = (char*)d_ws;
  _Float16* h_nb16  = (_Float16*)ws;                       // 16 MB
  _Float16* h_enc16 = (_Float16*)(ws + (16u<<20));         // 2 MB
  float*    fusedp  = (float*)(ws + (18u<<20));            // 4 MB
  char* aux = ws + (22u<<20);
  _Float16* w1f    = (_Float16*)aux;                       // 152,064 B
  _Float16* w2f    = (_Float16*)(aux + 152064);            // 39,168 B
  _Float16* fus_wf = (_Float16*)(aux + 152064 + 39168);    // 41,984 B
  float*    v2bg   = (float*)(aux + 233216);               // 8,192 B
  float*    bgmaxp = (float*)(aux + 241408);               // 128 B
  _Float16* whhp   = (_Float16*)(aux + 241536);            // 131,072 B
  float*    biasp  = (float*)(aux + 241536 + 131072);      // 2,048 B

  prep_kernel<<<64, 256, 0, stream>>>(w1, b1, w2, b2, fus_w,
                                      dec_w_ih, dec_w_hh, dec_b_ih, dec_b_hh,
                                      out_w, out_b,
                                      w1f, w2f, fus_wf, whhp, biasp, v2bg, bgmaxp);
  lstm_all<<<2304, 512, 0, stream>>>(target, neigh,
                                     enc_w_ih, enc_w_hh, enc_b_ih, enc_b_hh,
                                     nb_w_ih, nb_w_hh, nb_b_ih, nb_b_hh,
                                     h_enc16, h_nb16);
  social_fuse<<<512, 512, 0, stream>>>(h_enc16, h_nb16, w1f, w2f, fus_wf,
                                       b1, v2bg, bgmaxp, fus_b, fusedp);
  dec_mfma<<<256, 512, 0, stream>>>(fusedp, whhp, biasp, dec_w_ih,
                                    out_w, out_b, (float*)d_out);
}

// Round 9
// 469.874 us; speedup vs baseline: 1.0234x; 1.0187x over previous
//
#include <hip/hip_runtime.h>

typedef _Float16 half8  __attribute__((ext_vector_type(8)));
typedef _Float16 half4v __attribute__((ext_vector_type(4)));
typedef float  floatx4  __attribute__((ext_vector_type(4)));
typedef float  floatx2  __attribute__((ext_vector_type(2)));

#define MFMA16(A,B,C) __builtin_amdgcn_mfma_f32_16x16x32_f16((A),(B),(C),0,0,0)

#define L2E  1.4426950408889634f
#define L2E2 2.8853900817779268f

__device__ __forceinline__ float rcpf(float x){ return __builtin_amdgcn_rcpf(x); }
__device__ __forceinline__ float ex2(float x){ return __builtin_amdgcn_exp2f(x); }
__device__ __forceinline__ float tanh_raw(float c){
  return 1.0f - 2.0f*rcpf(1.0f + ex2(L2E2*c));
}
__device__ __forceinline__ half8 ld8(const _Float16* p){
  half4v a = *(const half4v*)p;
  half4v b = *(const half4v*)(p+4);
  return __builtin_shufflevector(a,b,0,1,2,3,4,5,6,7);
}

__device__ __forceinline__ floatx2 ex2v(floatx2 x){
  floatx2 r; r[0]=ex2(x[0]); r[1]=ex2(x[1]); return r;
}
__device__ __forceinline__ floatx2 rcpv(floatx2 x){
  floatx2 r; r[0]=rcpf(x[0]); r[1]=rcpf(x[1]); return r;
}

// Fused LSTM cell on a PAIR of cells (float2 ext-vector -> VOP3P
// v_pk_{add,mul,fma}_f32 for the non-trans arithmetic).
// 7 trans/cell (5 ex2 + 2 rcp), exact algebra.
__device__ __forceinline__ floatx2 lstm_cell2(floatx2 yi, floatx2 yf,
                                              floatx2 yg, floatx2 yo,
                                              floatx2& c){
  floatx2 A = ex2v(-yi), B = ex2v(-yf), C = ex2v(yg);
  const floatx2 one = {1.f, 1.f};
  floatx2 P = (one + A)*(one + C);
  floatx2 Q = one + B;
  floatx2 r = rcpv(P*Q);
  floatx2 cn = (c*P + (C - one)*Q)*r;
  c = cn;
  floatx2 F = ex2v(-yo), E = ex2v(L2E2*cn);
  floatx2 r3 = rcpv((one + F)*(one + E));
  return (E - one)*r3;
}

// grid geometry tables (compile-time foldable)
static __device__ constexpr int DY[27] = {0,0,0,0,0,0,0,0, 1,1,1,1,1,1,1,1, 2,2, 3,3,3,4,4,4,5,5,5};
static __device__ constexpr int DX[27] = {0,1,2,3,4,5,6,7, 0,1,2,3,4,5,6,7, 0,1, 3,4,5,3,4,5,3,4,5};
static __device__ constexpr int PY[9]  = {0,0,0,0,0,0,0,1,4};
static __device__ constexpr int PX[9]  = {1,2,3,4,5,6,7,0,4};
static __device__ constexpr int OY[46] = {0,0,0,0,0,0,0,0, 1,1,1,1,1,1,1,1, 2,2,2,2,2,2,2,2,
                                          3,3,3,3,3,3,3, 4,4,4,4,4, 5,5,5,5,5, 6,6,6,6,6};
static __device__ constexpr int OX[46] = {0,1,2,3,4,5,6,7, 0,1,2,3,4,5,6,7, 0,1,2,3,4,5,6,7,
                                          0,1,2,3,4,5,6, 2,3,4,5,6, 2,3,4,5,6, 2,3,4,5,6};
__device__ constexpr int d1idx(int iy,int ix){
  return (iy<0||iy>7||ix<0||ix>7) ? -1 :
         (iy<=1) ? iy*8+ix :
         (iy==2 && ix<=1) ? 16+ix :
         (iy>=3 && iy<=5 && ix>=3 && ix<=5) ? 18+(iy-3)*3+(ix-3) : -1;
}

// ---------------------------------------------------------------------------
// Combined encoder: batch-32 per block, packed-pair cell, bxr hoist.
// Frozen since R7 (structural issue floor).
// ---------------------------------------------------------------------------
__global__ __launch_bounds__(512, 4) void lstm_all(
    const float* __restrict__ target, const float* __restrict__ neigh,
    const float* __restrict__ e_wih, const float* __restrict__ e_whh,
    const float* __restrict__ e_bih, const float* __restrict__ e_bhh,
    const float* __restrict__ n_wih, const float* __restrict__ n_whh,
    const float* __restrict__ n_bih, const float* __restrict__ n_bhh,
    _Float16* __restrict__ h_enc16, _Float16* __restrict__ h_nb16)
{
  __shared__ _Float16 h_lds[2][32][136];
  __shared__ _Float16 xf16[32][168];
  __shared__ __align__(16) _Float16 wihb[8][4][17][8];

  const int tid  = threadIdx.x;
  const int wv   = tid >> 6;
  const int lane = tid & 63;
  const int q    = lane >> 4;
  const int cb   = lane & 15;

  const bool enc = (blockIdx.x < 256);
  const float* x   = enc ? target : neigh;
  const float* wih = enc ? e_wih : n_wih;
  const float* whh = enc ? e_whh : n_whh;
  const float* bih = enc ? e_bih : n_bih;
  const float* bhh = enc ? e_bhh : n_bhh;
  _Float16* hout   = enc ? h_enc16 : h_nb16;
  const long base  = enc ? (long)blockIdx.x*32 : (long)(blockIdx.x-256)*32;

  for (int i = tid; i < 32*168; i += 512){
    int seq = i/168, rem = i%168, t = rem>>3, f = rem&7;
    float v = 0.f;
    if (t < 20) v = (f < 7) ? x[base*140 + seq*140 + t*7 + f] : 1.0f;
    xf16[seq][rem] = (_Float16)v;
  }
  for (int i = tid; i < 32*136; i += 512) ((_Float16*)h_lds)[i] = (_Float16)0.f;

  if (q == 0){
    #pragma unroll
    for (int g=0; g<4; ++g){
      const float sc = (g==2) ? L2E2 : L2E;
      const int col = g*128 + wv*16 + cb;
      _Float16* d = &wihb[wv][g][cb][0];
      #pragma unroll
      for (int j=0;j<7;++j) d[j] = (_Float16)(wih[col*7+j]*sc);
      d[7] = (_Float16)((bih[col]+bhh[col])*sc);
    }
  } else if (lane == 16){
    #pragma unroll
    for (int g=0; g<4; ++g){
      _Float16* d = &wihb[wv][g][16][0];
      #pragma unroll
      for (int j=0;j<8;++j) d[j] = (_Float16)0.f;
    }
  }

  half8 bfrag[4][4];
  #pragma unroll
  for (int g=0; g<4; ++g){
    const float sc = (g==2) ? L2E2 : L2E;
    const int col = g*128 + wv*16 + cb;
    #pragma unroll
    for (int kc=0; kc<4; ++kc){
      const float* src = whh + (long)col*128 + kc*32 + q*8;
      half8 f;
      #pragma unroll
      for (int j=0;j<8;++j) f[j] = (_Float16)(src[j]*sc);
      bfrag[g][kc] = f;
    }
  }
  __syncthreads();

  const _Float16* bxp = &wihb[wv][0][(q==0)?cb:16][0];
  const _Float16* zsrc = &wihb[wv][0][16][0];
  const _Float16* a0p = (q==0) ? &xf16[cb][0]    : zsrc;
  const _Float16* a1p = (q==0) ? &xf16[cb+16][0] : zsrc;
  const int astep = (q==0) ? 8 : 0;
  half8 a40 = *(const half8*)a0p; a0p += astep;
  half8 a41 = *(const half8*)a1p; a1p += astep;

  half8 bxr[4];
  #pragma unroll
  for (int g=0; g<4; ++g) bxr[g] = *(const half8*)(bxp + g*136);

  floatx2 c0[2] = {{0,0},{0,0}}, c1[2] = {{0,0},{0,0}};
  half4v hv0 = {0,0,0,0}, hv1 = {0,0,0,0};
  const floatx4 ZERO4 = {0.f,0.f,0.f,0.f};

  for (int t=0; t<20; ++t){
    // ---- subtile 0 (batch rows cb) ----
    {
      const _Float16* hrow = &h_lds[t&1][cb][0];
      floatx4 acc[4];
      #pragma unroll
      for (int g=0; g<4; ++g)
        acc[g] = MFMA16(bxr[g], a40, ZERO4);
      #pragma unroll
      for (int kc=0; kc<4; ++kc){
        half8 b = *(const half8*)(hrow + kc*32 + q*8);
        #pragma unroll
        for (int g=0; g<4; ++g)
          acc[g] = MFMA16(bfrag[g][kc], b, acc[g]);
      }
      #pragma unroll
      for (int rp=0; rp<2; ++rp){
        floatx2 yi = {acc[0][2*rp], acc[0][2*rp+1]};
        floatx2 yf = {acc[1][2*rp], acc[1][2*rp+1]};
        floatx2 yg = {acc[2][2*rp], acc[2][2*rp+1]};
        floatx2 yo = {acc[3][2*rp], acc[3][2*rp+1]};
        floatx2 h2 = lstm_cell2(yi, yf, yg, yo, c0[rp]);
        hv0[2*rp]   = (_Float16)h2[0];
        hv0[2*rp+1] = (_Float16)h2[1];
      }
      *(half4v*)&h_lds[(t+1)&1][cb][wv*16 + q*4] = hv0;
    }
    // ---- subtile 1 (batch rows cb+16) ----
    {
      const _Float16* hrow = &h_lds[t&1][cb+16][0];
      floatx4 acc[4];
      #pragma unroll
      for (int g=0; g<4; ++g)
        acc[g] = MFMA16(bxr[g], a41, ZERO4);
      #pragma unroll
      for (int kc=0; kc<4; ++kc){
        half8 b = *(const half8*)(hrow + kc*32 + q*8);
        #pragma unroll
        for (int g=0; g<4; ++g)
          acc[g] = MFMA16(bfrag[g][kc], b, acc[g]);
      }
      #pragma unroll
      for (int rp=0; rp<2; ++rp){
        floatx2 yi = {acc[0][2*rp], acc[0][2*rp+1]};
        floatx2 yf = {acc[1][2*rp], acc[1][2*rp+1]};
        floatx2 yg = {acc[2][2*rp], acc[2][2*rp+1]};
        floatx2 yo = {acc[3][2*rp], acc[3][2*rp+1]};
        floatx2 h2 = lstm_cell2(yi, yf, yg, yo, c1[rp]);
        hv1[2*rp]   = (_Float16)h2[0];
        hv1[2*rp+1] = (_Float16)h2[1];
      }
      *(half4v*)&h_lds[(t+1)&1][cb+16][wv*16 + q*4] = hv1;
    }
    a40 = *(const half8*)a0p; a0p += astep;
    a41 = *(const half8*)a1p; a1p += astep;
    __syncthreads();
  }

  *(half4v*)&hout[(base + cb)*128      + wv*16 + q*4] = hv0;
  *(half4v*)&hout[(base + cb + 16)*128 + wv*16 + q*4] = hv1;
}

// ---------------------------------------------------------------------------
// Prep: conv/fusion weight layouts + conv2 background + decoder fold.
// ---------------------------------------------------------------------------
__global__ void prep_kernel(const float* __restrict__ w1, const float* __restrict__ b1,
                            const float* __restrict__ w2, const float* __restrict__ b2,
                            const float* __restrict__ fus_w,
                            const float* __restrict__ dec_wih, const float* __restrict__ dec_whh,
                            const float* __restrict__ dec_bih, const float* __restrict__ dec_bhh,
                            const float* __restrict__ out_w, const float* __restrict__ out_b,
                            _Float16* __restrict__ w1f, _Float16* __restrict__ w2f,
                            _Float16* __restrict__ fus_wf,
                            _Float16* __restrict__ whhp, float* __restrict__ biasp,
                            float* __restrict__ v2bg, float* __restrict__ bgmax)
{
  const int tid = threadIdx.x;
  const int gid = blockIdx.x*256 + tid;
  const int gstride = gridDim.x*256;
  for (int i = gid; i < 9*64*128; i += gstride){
    int s = i>>13, rem = i&8191, c1 = rem>>7, ci = rem&127;
    w1f[s*8448 + c1*132 + ci] = (_Float16)w1[c1*1152 + ci*9 + s];
  }
  for (int i = gid; i < 9*32*64; i += gstride){
    int s = i>>11, rem = i&2047, c2 = rem>>6, ci = rem&63;
    w2f[s*2176 + c2*68 + ci] = (_Float16)w2[c2*576 + ci*9 + s];
  }
  for (int i = gid; i < 128*160; i += gstride){
    int n = i/160, k = i%160;
    fus_wf[n*164 + k] = (_Float16)fus_w[i];
  }
  for (int i = gid; i < 512*128; i += gstride){
    int col = i>>7, k = i&127;
    float sc = ((col>>7)==2) ? L2E2 : L2E;
    float v = dec_whh[i] + dec_wih[col*2+0]*out_w[k] + dec_wih[col*2+1]*out_w[128+k];
    whhp[i] = (_Float16)(v*sc);
  }
  for (int i = gid; i < 512; i += gstride){
    float sc = ((i>>7)==2) ? L2E2 : L2E;
    biasp[i] = (dec_bih[i] + dec_bhh[i] + dec_wih[i*2+0]*out_b[0]
                + dec_wih[i*2+1]*out_b[1])*sc;
  }
  if (blockIdx.x == 0){
    __shared__ float S[288];
    __shared__ int bgm[32];
    for (int i=tid;i<288;i+=256){
      int c2=i/9, s=i%9;
      float a=0.f;
      for (int ci=0;ci<64;++ci) a += w2[c2*576+ci*9+s]*fmaxf(b1[ci],0.f);
      S[i]=a;
    }
    if (tid<32) bgm[tid]=0;
    __syncthreads();
    for (int i=tid;i<2048;i+=256){
      int cell=i>>5, c2=i&31, y=cell>>3, xx=cell&7;
      float a=b2[c2];
      for (int dy=0;dy<3;++dy){ int iy=y+dy-1; if((unsigned)iy>7u) continue;
        for (int dx=0;dx<3;++dx){ int ix=xx+dx-1; if((unsigned)ix>7u) continue;
          a += S[c2*9+dy*3+dx]; } }
      v2bg[cell*32+c2]=a;
      bool aff = (y<=2) || (y==3 && xx<=6) || (y>=4 && y<=6 && xx>=2 && xx<=6);
      if(!aff) atomicMax(&bgm[c2], __float_as_int(fmaxf(a,0.f)));
    }
    __syncthreads();
    if (tid<32) bgmax[tid]=__int_as_float(bgm[tid]);
  }
}

// ---------------------------------------------------------------------------
// conv1 position-outer body: per position p, the 4 A-fragments are loaded
// ONCE and accumulated into all cells this wave owns (cell set is
// compile-time via HALF). Per-cell (p,kc) accumulation order identical to
// the cell-outer version -> bit-identical results, ~9x fewer A-side ld8.
// ---------------------------------------------------------------------------
template<int HALF>
__device__ __forceinline__ void conv1_half(
    const _Float16* __restrict__ vecs, _Float16* __restrict__ d1,
    const half8 (&bf1)[9][4], float b1v, float bg,
    int c1lane, int cb, int q)
{
  constexpr int NC = (HALF==0) ? 14 : 13;
  floatx4 C[NC];
  #pragma unroll
  for (int i=0;i<NC;++i) C[i] = floatx4{0.f,0.f,0.f,0.f};

  #pragma unroll
  for (int p=0;p<9;++p){
    const _Float16* ap = vecs + p*2112 + cb*132 + q*8;
    half8 a0 = ld8(ap), a1 = ld8(ap+32), a2 = ld8(ap+64), a3 = ld8(ap+96);
    #pragma unroll
    for (int i=0;i<NC;++i){
      const int ci = 2*i + HALF;
      const int y = DY[ci], x = DX[ci];
      const int dy = PY[p]-y+1, dx = PX[p]-x+1;
      if (dy>=0 && dy<3 && dx>=0 && dx<3){
        const int s = dy*3+dx;
        C[i] = MFMA16(a0, bf1[s][0], C[i]);
        C[i] = MFMA16(a1, bf1[s][1], C[i]);
        C[i] = MFMA16(a2, bf1[s][2], C[i]);
        C[i] = MFMA16(a3, bf1[s][3], C[i]);
      }
    }
  }
  #pragma unroll
  for (int i=0;i<NC;++i){
    const int ci = 2*i + HALF;
    _Float16* dp = d1 + ci*1088 + c1lane;
    #pragma unroll
    for (int r=0;r<4;++r)
      dp[(q*4+r)*68] = (_Float16)(fmaxf(b1v + C[i][r], 0.f) - bg);
  }
}

// ---------------------------------------------------------------------------
// Social pooling + sparse conv + maxpool + fusion — 512 threads / 8 waves.
// R9: conv1 restructured position-outer (conv1_half above); conv2/fusion
// unchanged.
// ---------------------------------------------------------------------------
__global__ __launch_bounds__(512, 1) void social_fuse(
    const _Float16* __restrict__ h_enc, const _Float16* __restrict__ h_nb,
    const _Float16* __restrict__ w1f, const _Float16* __restrict__ w2f,
    const _Float16* __restrict__ fus_wf,
    const float* __restrict__ b1, const float* __restrict__ v2bg,
    const float* __restrict__ bgmax, const float* __restrict__ fus_b,
    float* __restrict__ fused)
{
  __shared__ __align__(16) _Float16 vecs[9*16*132];
  __shared__ __align__(16) _Float16 d1[27*16*68];
  __shared__ __align__(16) _Float16 A16[16*164];
  __shared__ int pooled[512];

  const int tid  = threadIdx.x;
  const int wv   = tid >> 6;
  const int lane = tid & 63;
  const int q    = lane >> 4;
  const int cb   = lane & 15;
  const long base = (long)blockIdx.x * 16;

  for (int i=tid; i<9*16*32; i+=512){
    int p = i>>9, rem = i&511, bb = rem>>5, j = rem&31;
    const _Float16* src = (p<8) ? (h_nb + (((base+bb))*8 + p)*128 + j*4)
                                : (h_enc + (base+bb)*128 + j*4);
    *(unsigned long long*)(vecs + p*2112 + bb*132 + j*4) = *(const unsigned long long*)src;
  }
  for (int i=tid; i<512; i+=512){
    int bb=i>>5, j=i&31;
    *(unsigned long long*)(A16 + bb*164 + j*4) =
        *(const unsigned long long*)(h_enc + (base+bb)*128 + j*4);
  }
  for (int i=tid; i<512; i+=512) pooled[i] = __float_as_int(bgmax[i&31]);
  __syncthreads();

  // ---- conv1: wave = (c1-slice wv&3, cell-parity wv>>2), position-outer ----
  {
    const int c1lane = (wv&3)*16 + cb;
    const int half   = wv >> 2;
    half8 bf1[9][4];
    #pragma unroll
    for (int s=0;s<9;++s)
      #pragma unroll
      for (int kc=0;kc<4;++kc)
        bf1[s][kc] = ld8(w1f + s*8448 + c1lane*132 + kc*32 + q*8);
    const float b1v = b1[c1lane];
    const float bg  = fmaxf(b1v, 0.f);

    if (half == 0) conv1_half<0>(vecs, d1, bf1, b1v, bg, c1lane, cb, q);
    else           conv1_half<1>(vecs, d1, bf1, b1v, bg, c1lane, cb, q);
  }
  __syncthreads();

  // ---- conv2 + maxpool: out-cells split 8 ways ----
  {
    half8 bf2[9][2][2];
    #pragma unroll
    for (int s=0;s<9;++s)
      #pragma unroll
      for (int nt=0;nt<2;++nt)
        #pragma unroll
        for (int kc=0;kc<2;++kc)
          bf2[s][nt][kc] = ld8(w2f + s*2176 + (nt*16+cb)*68 + kc*32 + q*8);

    float rm0[4] = {0,0,0,0}, rm1[4] = {0,0,0,0};
    #pragma unroll
    for (int oc=0; oc<46; ++oc){
      if ((oc & 7) != wv) continue;
      const int y = OY[oc], x = OX[oc];
      const int cell = y*8+x;
      float v0 = v2bg[cell*32 + cb];
      float v1 = v2bg[cell*32 + 16 + cb];
      floatx4 C0 = {v0,v0,v0,v0}, C1 = {v1,v1,v1,v1};
      #pragma unroll
      for (int dy=0;dy<3;++dy)
        #pragma unroll
        for (int dx=0;dx<3;++dx){
          const int dc = d1idx(y+dy-1, x+dx-1);
          if (dc < 0) continue;
          const int s = dy*3+dx;
          const _Float16* ap = d1 + dc*1088 + cb*68 + q*8;
          #pragma unroll
          for (int kc=0;kc<2;++kc){
            half8 a = ld8(ap + kc*32);
            C0 = MFMA16(a, bf2[s][0][kc], C0);
            C1 = MFMA16(a, bf2[s][1][kc], C1);
          }
        }
      #pragma unroll
      for (int r=0;r<4;++r){
        rm0[r] = fmaxf(rm0[r], fmaxf(C0[r],0.f));
        rm1[r] = fmaxf(rm1[r], fmaxf(C1[r],0.f));
      }
    }
    #pragma unroll
    for (int r=0;r<4;++r){
      atomicMax(&pooled[(q*4+r)*32 + cb],      __float_as_int(rm0[r]));
      atomicMax(&pooled[(q*4+r)*32 + 16 + cb], __float_as_int(rm1[r]));
    }
  }
  __syncthreads();

  for (int i=tid;i<512;i+=512){
    int bb=i>>5, c2=i&31;
    A16[bb*164 + 128 + c2] = (_Float16)__int_as_float(pooled[i]);
  }
  __syncthreads();

  // ---- fusion: wave wv owns n-tile wv (16 outputs) ----
  {
    half8 bfF[5];
    #pragma unroll
    for (int kc=0;kc<5;++kc)
      bfF[kc] = ld8(fus_wf + (wv*16+cb)*164 + kc*32 + q*8);
    const float fb = fus_b[wv*16+cb];
    floatx4 C0 = {0.f,0.f,0.f,0.f};
    #pragma unroll
    for (int kc=0;kc<5;++kc){
      half8 a = ld8(A16 + cb*164 + kc*32 + q*8);
      C0 = MFMA16(a, bfF[kc], C0);
    }
    #pragma unroll
    for (int r=0;r<4;++r){
      const long row = base + q*4 + r;
      fused[row*128 + wv*16+cb] = tanh_raw(C0[r]+fb);
    }
  }
}

// ---------------------------------------------------------------------------
// Decoder with folded feedback, batch-32 per block (frozen from R8).
// ---------------------------------------------------------------------------
__global__ __launch_bounds__(512, 4) void dec_mfma(
    const float* __restrict__ fused,
    const _Float16* __restrict__ whhp, const float* __restrict__ biasp,
    const float* __restrict__ w_ih,
    const float* __restrict__ out_w, const float* __restrict__ out_b,
    float* __restrict__ out)
{
  __shared__ _Float16 h_lds[2][32][136];
  __shared__ __align__(16) _Float16 wib[8][4][17][8];
  __shared__ float ow_lds[2][128];
  __shared__ float pred_lds[32][2];

  const int tid  = threadIdx.x;
  const int wv   = tid >> 6;
  const int lane = tid & 63;
  const int q    = lane >> 4;
  const int cb   = lane & 15;
  const long base = (long)blockIdx.x * 32;

  for (int i=tid;i<256;i+=512) ow_lds[i>>7][i&127] = out_w[i];
  for (int i=tid;i<4096;i+=512) h_lds[0][i>>7][i&127] = (_Float16)fused[base*128 + i];

  if (q == 0){
    #pragma unroll
    for (int g=0; g<4; ++g){
      const float sc = (g==2) ? L2E2 : L2E;
      const int col = g*128 + wv*16 + cb;
      _Float16* d = &wib[wv][g][cb][0];
      d[0] = (_Float16)(-w_ih[col*2+0]*sc);
      d[1] = (_Float16)(-w_ih[col*2+1]*sc);
      #pragma unroll
      for (int j=2;j<8;++j) d[j] = (_Float16)0.f;
    }
  } else if (lane == 16){
    #pragma unroll
    for (int g=0; g<4; ++g){
      _Float16* d = &wib[wv][g][16][0];
      #pragma unroll
      for (int j=0;j<8;++j) d[j] = (_Float16)0.f;
    }
  }

  half8 bfrag[4][4];
  float bias_r[4][4];
  #pragma unroll
  for (int g=0; g<4; ++g){
    const int col = g*128 + wv*16 + cb;
    #pragma unroll
    for (int r=0; r<4; ++r) bias_r[g][r] = biasp[g*128 + wv*16 + q*4 + r];
    #pragma unroll
    for (int kc=0; kc<4; ++kc)
      bfrag[g][kc] = ld8(whhp + (long)col*128 + kc*32 + q*8);
  }
  float ob0 = out_b[0], ob1 = out_b[1];
  __syncthreads();

  {
    int pair = tid>>3, part = tid&7;       // 64 pairs: m=0..31, oc=0..1
    int m = pair>>1, oc = pair&1;
    const float* owp = ow_lds[oc];
    float v = 0.f;
    #pragma unroll
    for (int k=part*16; k<part*16+16; ++k) v += owp[k]*(float)h_lds[0][m][k];
    v += __shfl_down(v, 4, 8);
    v += __shfl_down(v, 2, 8);
    v += __shfl_down(v, 1, 8);
    if (part==0) pred_lds[m][oc] = v + (oc ? ob1 : ob0);
  }
  __syncthreads();

  const _Float16* wibp = &wib[wv][0][(q==0)?cb:16][0];
  floatx2 c0[2] = {{0,0},{0,0}}, c1[2] = {{0,0},{0,0}};
  half4v hv0, hv1;

  for (int t=0; t<25; ++t){
    // ---- subtile 0 (batch rows cb) ----
    {
      const _Float16* hrow = &h_lds[t&1][cb][0];
      floatx4 acc[4];
      #pragma unroll
      for (int g=0; g<4; ++g)
        #pragma unroll
        for (int r=0; r<4; ++r) acc[g][r] = bias_r[g][r];
      if (t == 0){
        half8 pb = {0,0,0,0,0,0,0,0};
        if (q == 0){
          pb[0] = (_Float16)pred_lds[cb][0];
          pb[1] = (_Float16)pred_lds[cb][1];
        }
        #pragma unroll
        for (int g=0; g<4; ++g){
          half8 w = *(const half8*)(wibp + g*136);
          acc[g] = MFMA16(w, pb, acc[g]);
        }
      }
      #pragma unroll
      for (int kc=0; kc<4; ++kc){
        half8 b = *(const half8*)(hrow + kc*32 + q*8);
        #pragma unroll
        for (int g=0; g<4; ++g)
          acc[g] = MFMA16(bfrag[g][kc], b, acc[g]);
      }
      #pragma unroll
      for (int rp=0; rp<2; ++rp){
        floatx2 yi = {acc[0][2*rp], acc[0][2*rp+1]};
        floatx2 yf = {acc[1][2*rp], acc[1][2*rp+1]};
        floatx2 yg = {acc[2][2*rp], acc[2][2*rp+1]};
        floatx2 yo = {acc[3][2*rp], acc[3][2*rp+1]};
        floatx2 h2 = lstm_cell2(yi, yf, yg, yo, c0[rp]);
        hv0[2*rp]   = (_Float16)h2[0];
        hv0[2*rp+1] = (_Float16)h2[1];
      }
      *(half4v*)&h_lds[(t+1)&1][cb][wv*16 + q*4] = hv0;
    }
    // ---- subtile 1 (batch rows cb+16) ----
    {
      const _Float16* hrow = &h_lds[t&1][cb+16][0];
      floatx4 acc[4];
      #pragma unroll
      for (int g=0; g<4; ++g)
        #pragma unroll
        for (int r=0; r<4; ++r) acc[g][r] = bias_r[g][r];
      if (t == 0){
        half8 pb = {0,0,0,0,0,0,0,0};
        if (q == 0){
          pb[0] = (_Float16)pred_lds[cb+16][0];
          pb[1] = (_Float16)pred_lds[cb+16][1];
        }
        #pragma unroll
        for (int g=0; g<4; ++g){
          half8 w = *(const half8*)(wibp + g*136);
          acc[g] = MFMA16(w, pb, acc[g]);
        }
      }
      #pragma unroll
      for (int kc=0; kc<4; ++kc){
        half8 b = *(const half8*)(hrow + kc*32 + q*8);
        #pragma unroll
        for (int g=0; g<4; ++g)
          acc[g] = MFMA16(bfrag[g][kc], b, acc[g]);
      }
      #pragma unroll
      for (int rp=0; rp<2; ++rp){
        floatx2 yi = {acc[0][2*rp], acc[0][2*rp+1]};
        floatx2 yf = {acc[1][2*rp], acc[1][2*rp+1]};
        floatx2 yg = {acc[2][2*rp], acc[2][2*rp+1]};
        floatx2 yo = {acc[3][2*rp], acc[3][2*rp+1]};
        floatx2 h2 = lstm_cell2(yi, yf, yg, yo, c1[rp]);
        hv1[2*rp]   = (_Float16)h2[0];
        hv1[2*rp+1] = (_Float16)h2[1];
      }
      *(half4v*)&h_lds[(t+1)&1][cb+16][wv*16 + q*4] = hv1;
    }
    __syncthreads();
    {
      _Float16 (*hw)[136] = h_lds[(t+1)&1];
      int pair = tid>>3, part = tid&7;     // 64 pairs: m=0..31, oc=0..1
      int m = pair>>1, oc = pair&1;
      const float* owp = ow_lds[oc];
      float v = 0.f;
      #pragma unroll
      for (int k=part*16; k<part*16+16; ++k) v += owp[k]*(float)hw[m][k];
      v += __shfl_down(v, 4, 8);
      v += __shfl_down(v, 2, 8);
      v += __shfl_down(v, 1, 8);
      if (part==0)
        out[(base+m)*50 + t*2 + oc] = v + (oc ? ob1 : ob0);
    }
  }
}

// ---------------------------------------------------------------------------
extern "C" void kernel_launch(void* const* d_in, const int* in_sizes, int n_in,
                              void* d_out, int out_size, void* d_ws, size_t ws_size,
                              hipStream_t stream)
{
  (void)in_sizes; (void)n_in; (void)out_size; (void)ws_size;
  const float* target   = (const float*)d_in[0];
  const float* neigh    = (const float*)d_in[1];
  const float* enc_w_ih = (const float*)d_in[4];
  const float* enc_w_hh = (const float*)d_in[5];
  const float* enc_b_ih = (const float*)d_in[6];
  const float* enc_b_hh = (const float*)d_in[7];
  const float* nb_w_ih  = (const float*)d_in[8];
  const float* nb_w_hh  = (const float*)d_in[9];
  const float* nb_b_ih  = (const float*)d_in[10];
  const float* nb_b_hh  = (const float*)d_in[11];
  const float* w1       = (const float*)d_in[12];
  const float* b1       = (const float*)d_in[13];
  const float* w2       = (const float*)d_in[14];
  const float* b2       = (const float*)d_in[15];
  const float* fus_w    = (const float*)d_in[16];
  const float* fus_b    = (const float*)d_in[17];
  const float* dec_w_ih = (const float*)d_in[18];
  const float* dec_w_hh = (const float*)d_in[19];
  const float* dec_b_ih = (const float*)d_in[20];
  const float* dec_b_hh = (const float*)d_in[21];
  const float* out_w    = (const float*)d_in[22];
  const float* out_b    = (const float*)d_in[23];

  char* ws = (char*)d_ws;
  _Float16* h_nb16  = (_Float16*)ws;                       // 16 MB
  _Float16* h_enc16 = (_Float16*)(ws + (16u<<20));         // 2 MB
  float*    fusedp  = (float*)(ws + (18u<<20));            // 4 MB
  char* aux = ws + (22u<<20);
  _Float16* w1f    = (_Float16*)aux;                       // 152,064 B
  _Float16* w2f    = (_Float16*)(aux + 152064);            // 39,168 B
  _Float16* fus_wf = (_Float16*)(aux + 152064 + 39168);    // 41,984 B
  float*    v2bg   = (float*)(aux + 233216);               // 8,192 B
  float*    bgmaxp = (float*)(aux + 241408);               // 128 B
  _Float16* whhp   = (_Float16*)(aux + 241536);            // 131,072 B
  float*    biasp  = (float*)(aux + 241536 + 131072);      // 2,048 B

  prep_kernel<<<64, 256, 0, stream>>>(w1, b1, w2, b2, fus_w,
                                      dec_w_ih, dec_w_hh, dec_b_ih, dec_b_hh,
                                      out_w, out_b,
                                      w1f, w2f, fus_wf, whhp, biasp, v2bg, bgmaxp);
  lstm_all<<<2304, 512, 0, stream>>>(target, neigh,
                                     enc_w_ih, enc_w_hh, enc_b_ih, enc_b_hh,
                                     nb_w_ih, nb_w_hh, nb_b_ih, nb_b_hh,
                                     h_enc16, h_nb16);
  social_fuse<<<512, 512, 0, stream>>>(h_enc16, h_nb16, w1f, w2f, fus_wf,
                                       b1, v2bg, bgmaxp, fus_b, fusedp);
  dec_mfma<<<256, 512, 0, stream>>>(fusedp, whhp, biasp, dec_w_ih,
                                    out_w, out_b, (float*)d_out);
}

// Round 11
// 452.026 us; speedup vs baseline: 1.0639x; 1.0395x over previous
//
#include <hip/hip_runtime.h>

typedef _Float16 half8  __attribute__((ext_vector_type(8)));
typedef _Float16 half4v __attribute__((ext_vector_type(4)));
typedef float  floatx4  __attribute__((ext_vector_type(4)));
typedef float  floatx2  __attribute__((ext_vector_type(2)));

#define MFMA16(A,B,C) __builtin_amdgcn_mfma_f32_16x16x32_f16((A),(B),(C),0,0,0)

#define L2E  1.4426950408889634f
#define L2E2 2.8853900817779268f

__device__ __forceinline__ float rcpf(float x){ return __builtin_amdgcn_rcpf(x); }
__device__ __forceinline__ float ex2(float x){ return __builtin_amdgcn_exp2f(x); }
__device__ __forceinline__ float tanh_raw(float c){
  return 1.0f - 2.0f*rcpf(1.0f + ex2(L2E2*c));
}
__device__ __forceinline__ half8 ld8(const _Float16* p){
  half4v a = *(const half4v*)p;
  half4v b = *(const half4v*)(p+4);
  return __builtin_shufflevector(a,b,0,1,2,3,4,5,6,7);
}

__device__ __forceinline__ floatx2 ex2v(floatx2 x){
  floatx2 r; r[0]=ex2(x[0]); r[1]=ex2(x[1]); return r;
}
__device__ __forceinline__ floatx2 rcpv(floatx2 x){
  floatx2 r; r[0]=rcpf(x[0]); r[1]=rcpf(x[1]); return r;
}

// Fused LSTM cell on a PAIR of cells (float2 -> VOP3P packed non-trans math).
// 7 trans/cell (5 ex2 + 2 rcp), exact algebra.
__device__ __forceinline__ floatx2 lstm_cell2(floatx2 yi, floatx2 yf,
                                              floatx2 yg, floatx2 yo,
                                              floatx2& c){
  floatx2 A = ex2v(-yi), B = ex2v(-yf), C = ex2v(yg);
  const floatx2 one = {1.f, 1.f};
  floatx2 P = (one + A)*(one + C);
  floatx2 Q = one + B;
  floatx2 r = rcpv(P*Q);
  floatx2 cn = (c*P + (C - one)*Q)*r;
  c = cn;
  floatx2 F = ex2v(-yo), E = ex2v(L2E2*cn);
  floatx2 r3 = rcpv((one + F)*(one + E));
  return (E - one)*r3;
}

// grid geometry tables (compile-time foldable)
static __device__ constexpr int DY[27] = {0,0,0,0,0,0,0,0, 1,1,1,1,1,1,1,1, 2,2, 3,3,3,4,4,4,5,5,5};
static __device__ constexpr int DX[27] = {0,1,2,3,4,5,6,7, 0,1,2,3,4,5,6,7, 0,1, 3,4,5,3,4,5,3,4,5};
static __device__ constexpr int PY[9]  = {0,0,0,0,0,0,0,1,4};
static __device__ constexpr int PX[9]  = {1,2,3,4,5,6,7,0,4};
static __device__ constexpr int OY[46] = {0,0,0,0,0,0,0,0, 1,1,1,1,1,1,1,1, 2,2,2,2,2,2,2,2,
                                          3,3,3,3,3,3,3, 4,4,4,4,4, 5,5,5,5,5, 6,6,6,6,6};
static __device__ constexpr int OX[46] = {0,1,2,3,4,5,6,7, 0,1,2,3,4,5,6,7, 0,1,2,3,4,5,6,7,
                                          0,1,2,3,4,5,6, 2,3,4,5,6, 2,3,4,5,6, 2,3,4,5,6};
__device__ constexpr int d1idx(int iy,int ix){
  return (iy<0||iy>7||ix<0||ix>7) ? -1 :
         (iy<=1) ? iy*8+ix :
         (iy==2 && ix<=1) ? 16+ix :
         (iy>=3 && iy<=5 && ix>=3 && ix<=5) ? 18+(iy-3)*3+(ix-3) : -1;
}

// ---------------------------------------------------------------------------
// Combined encoder + prep: blocks [0,2304) run the batch-32 LSTM encoder
// (frozen since R7 — structural issue floor); blocks [2304,2368) run the
// prep path (weight relayouts, conv2 background, decoder fold), filling the
// encoder's half-empty tail round. Stream order still guarantees prep
// completes before social_fuse launches.
// ---------------------------------------------------------------------------
__global__ __launch_bounds__(512, 4) void lstm_all(
    const float* __restrict__ target, const float* __restrict__ neigh,
    const float* __restrict__ e_wih, const float* __restrict__ e_whh,
    const float* __restrict__ e_bih, const float* __restrict__ e_bhh,
    const float* __restrict__ n_wih, const float* __restrict__ n_whh,
    const float* __restrict__ n_bih, const float* __restrict__ n_bhh,
    _Float16* __restrict__ h_enc16, _Float16* __restrict__ h_nb16,
    const float* __restrict__ w1, const float* __restrict__ b1,
    const float* __restrict__ w2, const float* __restrict__ b2,
    const float* __restrict__ fus_w,
    const float* __restrict__ dec_wih, const float* __restrict__ dec_whh,
    const float* __restrict__ dec_bih, const float* __restrict__ dec_bhh,
    const float* __restrict__ out_w, const float* __restrict__ out_b,
    _Float16* __restrict__ w1f, _Float16* __restrict__ w2f,
    _Float16* __restrict__ fus_wf,
    _Float16* __restrict__ whhp, float* __restrict__ biasp,
    float* __restrict__ v2bg, float* __restrict__ bgmax)
{
  __shared__ _Float16 h_lds[2][32][136];
  __shared__ _Float16 xf16[32][168];
  __shared__ __align__(16) _Float16 wihb[8][4][17][8];
  __shared__ float S2[288];
  __shared__ int bgm[32];

  const int tid  = threadIdx.x;

  // ---------------- prep path (blocks 2304+) ----------------
  if (blockIdx.x >= 2304){
    const int pb = blockIdx.x - 2304;
    const int gid = pb*512 + tid;
    const int gstride = 64*512;
    for (int i = gid; i < 9*64*128; i += gstride){
      int s = i>>13, rem = i&8191, c1 = rem>>7, ci = rem&127;
      w1f[s*8448 + c1*132 + ci] = (_Float16)w1[c1*1152 + ci*9 + s];
    }
    for (int i = gid; i < 9*32*64; i += gstride){
      int s = i>>11, rem = i&2047, c2 = rem>>6, ci = rem&63;
      w2f[s*2176 + c2*68 + ci] = (_Float16)w2[c2*576 + ci*9 + s];
    }
    for (int i = gid; i < 128*160; i += gstride){
      int n = i/160, k = i%160;
      fus_wf[n*164 + k] = (_Float16)fus_w[i];
    }
    for (int i = gid; i < 512*128; i += gstride){
      int col = i>>7, k = i&127;
      float sc = ((col>>7)==2) ? L2E2 : L2E;
      float v = dec_whh[i] + dec_wih[col*2+0]*out_w[k] + dec_wih[col*2+1]*out_w[128+k];
      whhp[i] = (_Float16)(v*sc);
    }
    for (int i = gid; i < 512; i += gstride){
      float sc = ((i>>7)==2) ? L2E2 : L2E;
      biasp[i] = (dec_bih[i] + dec_bhh[i] + dec_wih[i*2+0]*out_b[0]
                  + dec_wih[i*2+1]*out_b[1])*sc;
    }
    if (pb == 0){
      for (int i=tid;i<288;i+=512){
        int c2=i/9, s=i%9;
        float a=0.f;
        for (int ci=0;ci<64;++ci) a += w2[c2*576+ci*9+s]*fmaxf(b1[ci],0.f);
        S2[i]=a;
      }
      if (tid<32) bgm[tid]=0;
      __syncthreads();
      for (int i=tid;i<2048;i+=512){
        int cell=i>>5, c2=i&31, y=cell>>3, xx=cell&7;
        float a=b2[c2];
        for (int dy=0;dy<3;++dy){ int iy=y+dy-1; if((unsigned)iy>7u) continue;
          for (int dx=0;dx<3;++dx){ int ix=xx+dx-1; if((unsigned)ix>7u) continue;
            a += S2[c2*9+dy*3+dx]; } }
        v2bg[cell*32+c2]=a;
        bool aff = (y<=2) || (y==3 && xx<=6) || (y>=4 && y<=6 && xx>=2 && xx<=6);
        if(!aff) atomicMax(&bgm[c2], __float_as_int(fmaxf(a,0.f)));
      }
      __syncthreads();
      if (tid<32) bgmax[tid]=__int_as_float(bgm[tid]);
    }
    return;
  }

  // ---------------- encoder path (blocks 0..2303) ----------------
  const int wv   = tid >> 6;
  const int lane = tid & 63;
  const int q    = lane >> 4;
  const int cb   = lane & 15;

  const bool enc = (blockIdx.x < 256);
  const float* x   = enc ? target : neigh;
  const float* wih = enc ? e_wih : n_wih;
  const float* whh = enc ? e_whh : n_whh;
  const float* bih = enc ? e_bih : n_bih;
  const float* bhh = enc ? e_bhh : n_bhh;
  _Float16* hout   = enc ? h_enc16 : h_nb16;
  const long base  = enc ? (long)blockIdx.x*32 : (long)(blockIdx.x-256)*32;

  for (int i = tid; i < 32*168; i += 512){
    int seq = i/168, rem = i%168, t = rem>>3, f = rem&7;
    float v = 0.f;
    if (t < 20) v = (f < 7) ? x[base*140 + seq*140 + t*7 + f] : 1.0f;
    xf16[seq][rem] = (_Float16)v;
  }
  for (int i = tid; i < 32*136; i += 512) ((_Float16*)h_lds)[i] = (_Float16)0.f;

  if (q == 0){
    #pragma unroll
    for (int g=0; g<4; ++g){
      const float sc = (g==2) ? L2E2 : L2E;
      const int col = g*128 + wv*16 + cb;
      _Float16* d = &wihb[wv][g][cb][0];
      #pragma unroll
      for (int j=0;j<7;++j) d[j] = (_Float16)(wih[col*7+j]*sc);
      d[7] = (_Float16)((bih[col]+bhh[col])*sc);
    }
  } else if (lane == 16){
    #pragma unroll
    for (int g=0; g<4; ++g){
      _Float16* d = &wihb[wv][g][16][0];
      #pragma unroll
      for (int j=0;j<8;++j) d[j] = (_Float16)0.f;
    }
  }

  half8 bfrag[4][4];
  #pragma unroll
  for (int g=0; g<4; ++g){
    const float sc = (g==2) ? L2E2 : L2E;
    const int col = g*128 + wv*16 + cb;
    #pragma unroll
    for (int kc=0; kc<4; ++kc){
      const float* src = whh + (long)col*128 + kc*32 + q*8;
      half8 f;
      #pragma unroll
      for (int j=0;j<8;++j) f[j] = (_Float16)(src[j]*sc);
      bfrag[g][kc] = f;
    }
  }
  __syncthreads();

  const _Float16* bxp = &wihb[wv][0][(q==0)?cb:16][0];
  const _Float16* zsrc = &wihb[wv][0][16][0];
  const _Float16* a0p = (q==0) ? &xf16[cb][0]    : zsrc;
  const _Float16* a1p = (q==0) ? &xf16[cb+16][0] : zsrc;
  const int astep = (q==0) ? 8 : 0;
  half8 a40 = *(const half8*)a0p; a0p += astep;
  half8 a41 = *(const half8*)a1p; a1p += astep;

  half8 bxr[4];
  #pragma unroll
  for (int g=0; g<4; ++g) bxr[g] = *(const half8*)(bxp + g*136);

  floatx2 c0[2] = {{0,0},{0,0}}, c1[2] = {{0,0},{0,0}};
  half4v hv0 = {0,0,0,0}, hv1 = {0,0,0,0};
  const floatx4 ZERO4 = {0.f,0.f,0.f,0.f};

  for (int t=0; t<20; ++t){
    // ---- subtile 0 (batch rows cb) ----
    {
      const _Float16* hrow = &h_lds[t&1][cb][0];
      floatx4 acc[4];
      #pragma unroll
      for (int g=0; g<4; ++g)
        acc[g] = MFMA16(bxr[g], a40, ZERO4);
      #pragma unroll
      for (int kc=0; kc<4; ++kc){
        half8 b = *(const half8*)(hrow + kc*32 + q*8);
        #pragma unroll
        for (int g=0; g<4; ++g)
          acc[g] = MFMA16(bfrag[g][kc], b, acc[g]);
      }
      #pragma unroll
      for (int rp=0; rp<2; ++rp){
        floatx2 yi = {acc[0][2*rp], acc[0][2*rp+1]};
        floatx2 yf = {acc[1][2*rp], acc[1][2*rp+1]};
        floatx2 yg = {acc[2][2*rp], acc[2][2*rp+1]};
        floatx2 yo = {acc[3][2*rp], acc[3][2*rp+1]};
        floatx2 h2 = lstm_cell2(yi, yf, yg, yo, c0[rp]);
        hv0[2*rp]   = (_Float16)h2[0];
        hv0[2*rp+1] = (_Float16)h2[1];
      }
      *(half4v*)&h_lds[(t+1)&1][cb][wv*16 + q*4] = hv0;
    }
    // ---- subtile 1 (batch rows cb+16) ----
    {
      const _Float16* hrow = &h_lds[t&1][cb+16][0];
      floatx4 acc[4];
      #pragma unroll
      for (int g=0; g<4; ++g)
        acc[g] = MFMA16(bxr[g], a41, ZERO4);
      #pragma unroll
      for (int kc=0; kc<4; ++kc){
        half8 b = *(const half8*)(hrow + kc*32 + q*8);
        #pragma unroll
        for (int g=0; g<4; ++g)
          acc[g] = MFMA16(bfrag[g][kc], b, acc[g]);
      }
      #pragma unroll
      for (int rp=0; rp<2; ++rp){
        floatx2 yi = {acc[0][2*rp], acc[0][2*rp+1]};
        floatx2 yf = {acc[1][2*rp], acc[1][2*rp+1]};
        floatx2 yg = {acc[2][2*rp], acc[2][2*rp+1]};
        floatx2 yo = {acc[3][2*rp], acc[3][2*rp+1]};
        floatx2 h2 = lstm_cell2(yi, yf, yg, yo, c1[rp]);
        hv1[2*rp]   = (_Float16)h2[0];
        hv1[2*rp+1] = (_Float16)h2[1];
      }
      *(half4v*)&h_lds[(t+1)&1][cb+16][wv*16 + q*4] = hv1;
    }
    a40 = *(const half8*)a0p; a0p += astep;
    a41 = *(const half8*)a1p; a1p += astep;
    __syncthreads();
  }

  *(half4v*)&hout[(base + cb)*128      + wv*16 + q*4] = hv0;
  *(half4v*)&hout[(base + cb + 16)*128 + wv*16 + q*4] = hv1;
}

// ---------------------------------------------------------------------------
// conv1 position-outer body (kept from R9 — null on perf but fewer LDS reads,
// bit-identical results).
// ---------------------------------------------------------------------------
template<int HALF>
__device__ __forceinline__ void conv1_half(
    const _Float16* __restrict__ vecs, _Float16* __restrict__ d1,
    const half8 (&bf1)[9][4], float b1v, float bg,
    int c1lane, int cb, int q)
{
  constexpr int NC = (HALF==0) ? 14 : 13;
  floatx4 C[NC];
  #pragma unroll
  for (int i=0;i<NC;++i) C[i] = floatx4{0.f,0.f,0.f,0.f};

  #pragma unroll
  for (int p=0;p<9;++p){
    const _Float16* ap = vecs + p*2112 + cb*132 + q*8;
    half8 a0 = ld8(ap), a1 = ld8(ap+32), a2 = ld8(ap+64), a3 = ld8(ap+96);
    #pragma unroll
    for (int i=0;i<NC;++i){
      const int ci = 2*i + HALF;
      const int y = DY[ci], x = DX[ci];
      const int dy = PY[p]-y+1, dx = PX[p]-x+1;
      if (dy>=0 && dy<3 && dx>=0 && dx<3){
        const int s = dy*3+dx;
        C[i] = MFMA16(a0, bf1[s][0], C[i]);
        C[i] = MFMA16(a1, bf1[s][1], C[i]);
        C[i] = MFMA16(a2, bf1[s][2], C[i]);
        C[i] = MFMA16(a3, bf1[s][3], C[i]);
      }
    }
  }
  #pragma unroll
  for (int i=0;i<NC;++i){
    const int ci = 2*i + HALF;
    _Float16* dp = d1 + ci*1088 + c1lane;
    #pragma unroll
    for (int r=0;r<4;++r)
      dp[(q*4+r)*68] = (_Float16)(fmaxf(b1v + C[i][r], 0.f) - bg);
  }
}

// ---------------------------------------------------------------------------
// Social pooling + sparse conv + maxpool + fusion — 512 threads / 8 waves.
// ---------------------------------------------------------------------------
__global__ __launch_bounds__(512, 1) void social_fuse(
    const _Float16* __restrict__ h_enc, const _Float16* __restrict__ h_nb,
    const _Float16* __restrict__ w1f, const _Float16* __restrict__ w2f,
    const _Float16* __restrict__ fus_wf,
    const float* __restrict__ b1, const float* __restrict__ v2bg,
    const float* __restrict__ bgmax, const float* __restrict__ fus_b,
    float* __restrict__ fused)
{
  __shared__ __align__(16) _Float16 vecs[9*16*132];
  __shared__ __align__(16) _Float16 d1[27*16*68];
  __shared__ __align__(16) _Float16 A16[16*164];
  __shared__ int pooled[512];

  const int tid  = threadIdx.x;
  const int wv   = tid >> 6;
  const int lane = tid & 63;
  const int q    = lane >> 4;
  const int cb   = lane & 15;
  const long base = (long)blockIdx.x * 16;

  for (int i=tid; i<9*16*32; i+=512){
    int p = i>>9, rem = i&511, bb = rem>>5, j = rem&31;
    const _Float16* src = (p<8) ? (h_nb + (((base+bb))*8 + p)*128 + j*4)
                                : (h_enc + (base+bb)*128 + j*4);
    *(unsigned long long*)(vecs + p*2112 + bb*132 + j*4) = *(const unsigned long long*)src;
  }
  for (int i=tid; i<512; i+=512){
    int bb=i>>5, j=i&31;
    *(unsigned long long*)(A16 + bb*164 + j*4) =
        *(const unsigned long long*)(h_enc + (base+bb)*128 + j*4);
  }
  for (int i=tid; i<512; i+=512) pooled[i] = __float_as_int(bgmax[i&31]);
  __syncthreads();

  // ---- conv1: wave = (c1-slice wv&3, cell-parity wv>>2), position-outer ----
  {
    const int c1lane = (wv&3)*16 + cb;
    const int half   = wv >> 2;
    half8 bf1[9][4];
    #pragma unroll
    for (int s=0;s<9;++s)
      #pragma unroll
      for (int kc=0;kc<4;++kc)
        bf1[s][kc] = ld8(w1f + s*8448 + c1lane*132 + kc*32 + q*8);
    const float b1v = b1[c1lane];
    const float bg  = fmaxf(b1v, 0.f);

    if (half == 0) conv1_half<0>(vecs, d1, bf1, b1v, bg, c1lane, cb, q);
    else           conv1_half<1>(vecs, d1, bf1, b1v, bg, c1lane, cb, q);
  }
  __syncthreads();

  // ---- conv2 + maxpool: out-cells split 8 ways ----
  {
    half8 bf2[9][2][2];
    #pragma unroll
    for (int s=0;s<9;++s)
      #pragma unroll
      for (int nt=0;nt<2;++nt)
        #pragma unroll
        for (int kc=0;kc<2;++kc)
          bf2[s][nt][kc] = ld8(w2f + s*2176 + (nt*16+cb)*68 + kc*32 + q*8);

    float rm0[4] = {0,0,0,0}, rm1[4] = {0,0,0,0};
    #pragma unroll
    for (int oc=0; oc<46; ++oc){
      if ((oc & 7) != wv) continue;
      const int y = OY[oc], x = OX[oc];
      const int cell = y*8+x;
      float v0 = v2bg[cell*32 + cb];
      float v1 = v2bg[cell*32 + 16 + cb];
      floatx4 C0 = {v0,v0,v0,v0}, C1 = {v1,v1,v1,v1};
      #pragma unroll
      for (int dy=0;dy<3;++dy)
        #pragma unroll
        for (int dx=0;dx<3;++dx){
          const int dc = d1idx(y+dy-1, x+dx-1);
          if (dc < 0) continue;
          const int s = dy*3+dx;
          const _Float16* ap = d1 + dc*1088 + cb*68 + q*8;
          #pragma unroll
          for (int kc=0;kc<2;++kc){
            half8 a = ld8(ap + kc*32);
            C0 = MFMA16(a, bf2[s][0][kc], C0);
            C1 = MFMA16(a, bf2[s][1][kc], C1);
          }
        }
      #pragma unroll
      for (int r=0;r<4;++r){
        rm0[r] = fmaxf(rm0[r], fmaxf(C0[r],0.f));
        rm1[r] = fmaxf(rm1[r], fmaxf(C1[r],0.f));
      }
    }
    #pragma unroll
    for (int r=0;r<4;++r){
      atomicMax(&pooled[(q*4+r)*32 + cb],      __float_as_int(rm0[r]));
      atomicMax(&pooled[(q*4+r)*32 + 16 + cb], __float_as_int(rm1[r]));
    }
  }
  __syncthreads();

  for (int i=tid;i<512;i+=512){
    int bb=i>>5, c2=i&31;
    A16[bb*164 + 128 + c2] = (_Float16)__int_as_float(pooled[i]);
  }
  __syncthreads();

  // ---- fusion: wave wv owns n-tile wv (16 outputs) ----
  {
    half8 bfF[5];
    #pragma unroll
    for (int kc=0;kc<5;++kc)
      bfF[kc] = ld8(fus_wf + (wv*16+cb)*164 + kc*32 + q*8);
    const float fb = fus_b[wv*16+cb];
    floatx4 C0 = {0.f,0.f,0.f,0.f};
    #pragma unroll
    for (int kc=0;kc<5;++kc){
      half8 a = ld8(A16 + cb*164 + kc*32 + q*8);
      C0 = MFMA16(a, bfF[kc], C0);
    }
    #pragma unroll
    for (int r=0;r<4;++r){
      const long row = base + q*4 + r;
      fused[row*128 + wv*16+cb] = tanh_raw(C0[r]+fb);
    }
  }
}

// ---------------------------------------------------------------------------
// Decoder with folded feedback, batch-32 per block (frozen from R8).
// ---------------------------------------------------------------------------
__global__ __launch_bounds__(512, 4) void dec_mfma(
    const float* __restrict__ fused,
    const _Float16* __restrict__ whhp, const float* __restrict__ biasp,
    const float* __restrict__ w_ih,
    const float* __restrict__ out_w, const float* __restrict__ out_b,
    float* __restrict__ out)
{
  __shared__ _Float16 h_lds[2][32][136];
  __shared__ __align__(16) _Float16 wib[8][4][17][8];
  __shared__ float ow_lds[2][128];
  __shared__ float pred_lds[32][2];

  const int tid  = threadIdx.x;
  const int wv   = tid >> 6;
  const int lane = tid & 63;
  const int q    = lane >> 4;
  const int cb   = lane & 15;
  const long base = (long)blockIdx.x * 32;

  for (int i=tid;i<256;i+=512) ow_lds[i>>7][i&127] = out_w[i];
  for (int i=tid;i<4096;i+=512) h_lds[0][i>>7][i&127] = (_Float16)fused[base*128 + i];

  if (q == 0){
    #pragma unroll
    for (int g=0; g<4; ++g){
      const float sc = (g==2) ? L2E2 : L2E;
      const int col = g*128 + wv*16 + cb;
      _Float16* d = &wib[wv][g][cb][0];
      d[0] = (_Float16)(-w_ih[col*2+0]*sc);
      d[1] = (_Float16)(-w_ih[col*2+1]*sc);
      #pragma unroll
      for (int j=2;j<8;++j) d[j] = (_Float16)0.f;
    }
  } else if (lane == 16){
    #pragma unroll
    for (int g=0; g<4; ++g){
      _Float16* d = &wib[wv][g][16][0];
      #pragma unroll
      for (int j=0;j<8;++j) d[j] = (_Float16)0.f;
    }
  }

  half8 bfrag[4][4];
  float bias_r[4][4];
  #pragma unroll
  for (int g=0; g<4; ++g){
    const int col = g*128 + wv*16 + cb;
    #pragma unroll
    for (int r=0; r<4; ++r) bias_r[g][r] = biasp[g*128 + wv*16 + q*4 + r];
    #pragma unroll
    for (int kc=0; kc<4; ++kc)
      bfrag[g][kc] = ld8(whhp + (long)col*128 + kc*32 + q*8);
  }
  float ob0 = out_b[0], ob1 = out_b[1];
  __syncthreads();

  {
    int pair = tid>>3, part = tid&7;       // 64 pairs: m=0..31, oc=0..1
    int m = pair>>1, oc = pair&1;
    const float* owp = ow_lds[oc];
    float v = 0.f;
    #pragma unroll
    for (int k=part*16; k<part*16+16; ++k) v += owp[k]*(float)h_lds[0][m][k];
    v += __shfl_down(v, 4, 8);
    v += __shfl_down(v, 2, 8);
    v += __shfl_down(v, 1, 8);
    if (part==0) pred_lds[m][oc] = v + (oc ? ob1 : ob0);
  }
  __syncthreads();

  const _Float16* wibp = &wib[wv][0][(q==0)?cb:16][0];
  floatx2 c0[2] = {{0,0},{0,0}}, c1[2] = {{0,0},{0,0}};
  half4v hv0, hv1;

  for (int t=0; t<25; ++t){
    // ---- subtile 0 (batch rows cb) ----
    {
      const _Float16* hrow = &h_lds[t&1][cb][0];
      floatx4 acc[4];
      #pragma unroll
      for (int g=0; g<4; ++g)
        #pragma unroll
        for (int r=0; r<4; ++r) acc[g][r] = bias_r[g][r];
      if (t == 0){
        half8 pb = {0,0,0,0,0,0,0,0};
        if (q == 0){
          pb[0] = (_Float16)pred_lds[cb][0];
          pb[1] = (_Float16)pred_lds[cb][1];
        }
        #pragma unroll
        for (int g=0; g<4; ++g){
          half8 w = *(const half8*)(wibp + g*136);
          acc[g] = MFMA16(w, pb, acc[g]);
        }
      }
      #pragma unroll
      for (int kc=0; kc<4; ++kc){
        half8 b = *(const half8*)(hrow + kc*32 + q*8);
        #pragma unroll
        for (int g=0; g<4; ++g)
          acc[g] = MFMA16(bfrag[g][kc], b, acc[g]);
      }
      #pragma unroll
      for (int rp=0; rp<2; ++rp){
        floatx2 yi = {acc[0][2*rp], acc[0][2*rp+1]};
        floatx2 yf = {acc[1][2*rp], acc[1][2*rp+1]};
        floatx2 yg = {acc[2][2*rp], acc[2][2*rp+1]};
        floatx2 yo = {acc[3][2*rp], acc[3][2*rp+1]};
        floatx2 h2 = lstm_cell2(yi, yf, yg, yo, c0[rp]);
        hv0[2*rp]   = (_Float16)h2[0];
        hv0[2*rp+1] = (_Float16)h2[1];
      }
      *(half4v*)&h_lds[(t+1)&1][cb][wv*16 + q*4] = hv0;
    }
    // ---- subtile 1 (batch rows cb+16) ----
    {
      const _Float16* hrow = &h_lds[t&1][cb+16][0];
      floatx4 acc[4];
      #pragma unroll
      for (int g=0; g<4; ++g)
        #pragma unroll
        for (int r=0; r<4; ++r) acc[g][r] = bias_r[g][r];
      if (t == 0){
        half8 pb = {0,0,0,0,0,0,0,0};
        if (q == 0){
          pb[0] = (_Float16)pred_lds[cb+16][0];
          pb[1] = (_Float16)pred_lds[cb+16][1];
        }
        #pragma unroll
        for (int g=0; g<4; ++g){
          half8 w = *(const half8*)(wibp + g*136);
          acc[g] = MFMA16(w, pb, acc[g]);
        }
      }
      #pragma unroll
      for (int kc=0; kc<4; ++kc){
        half8 b = *(const half8*)(hrow + kc*32 + q*8);
        #pragma unroll
        for (int g=0; g<4; ++g)
          acc[g] = MFMA16(bfrag[g][kc], b, acc[g]);
      }
      #pragma unroll
      for (int rp=0; rp<2; ++rp){
        floatx2 yi = {acc[0][2*rp], acc[0][2*rp+1]};
        floatx2 yf = {acc[1][2*rp], acc[1][2*rp+1]};
        floatx2 yg = {acc[2][2*rp], acc[2][2*rp+1]};
        floatx2 yo = {acc[3][2*rp], acc[3][2*rp+1]};
        floatx2 h2 = lstm_cell2(yi, yf, yg, yo, c1[rp]);
        hv1[2*rp]   = (_Float16)h2[0];
        hv1[2*rp+1] = (_Float16)h2[1];
      }
      *(half4v*)&h_lds[(t+1)&1][cb+16][wv*16 + q*4] = hv1;
    }
    __syncthreads();
    {
      _Float16 (*hw)[136] = h_lds[(t+1)&1];
      int pair = tid>>3, part = tid&7;     // 64 pairs: m=0..31, oc=0..1
      int m = pair>>1, oc = pair&1;
      const float* owp = ow_lds[oc];
      float v = 0.f;
      #pragma unroll
      for (int k=part*16; k<part*16+16; ++k) v += owp[k]*(float)hw[m][k];
      v += __shfl_down(v, 4, 8);
      v += __shfl_down(v, 2, 8);
      v += __shfl_down(v, 1, 8);
      if (part==0)
        out[(base+m)*50 + t*2 + oc] = v + (oc ? ob1 : ob0);
    }
  }
}

// ---------------------------------------------------------------------------
extern "C" void kernel_launch(void* const* d_in, const int* in_sizes, int n_in,
                              void* d_out, int out_size, void* d_ws, size_t ws_size,
                              hipStream_t stream)
{
  (void)in_sizes; (void)n_in; (void)out_size; (void)ws_size;
  const float* target   = (const float*)d_in[0];
  const float* neigh    = (const float*)d_in[1];
  const float* enc_w_ih = (const float*)d_in[4];
  const float* enc_w_hh = (const float*)d_in[5];
  const float* enc_b_ih = (const float*)d_in[6];
  const float* enc_b_hh = (const float*)d_in[7];
  const float* nb_w_ih  = (const float*)d_in[8];
  const float* nb_w_hh  = (const float*)d_in[9];
  const float* nb_b_ih  = (const float*)d_in[10];
  const float* nb_b_hh  = (const float*)d_in[11];
  const float* w1       = (const float*)d_in[12];
  const float* b1       = (const float*)d_in[13];
  const float* w2       = (const float*)d_in[14];
  const float* b2       = (const float*)d_in[15];
  const float* fus_w    = (const float*)d_in[16];
  const float* fus_b    = (const float*)d_in[17];
  const float* dec_w_ih = (const float*)d_in[18];
  const float* dec_w_hh = (const float*)d_in[19];
  const float* dec_b_ih = (const float*)d_in[20];
  const float* dec_b_hh = (const float*)d_in[21];
  const float* out_w    = (const float*)d_in[22];
  const float* out_b    = (const float*)d_in[23];

  char* ws = (char*)d_ws;
  _Float16* h_nb16  = (_Float16*)ws;                       // 16 MB
  _Float16* h_enc16 = (_Float16*)(ws + (16u<<20));         // 2 MB
  float*    fusedp  = (float*)(ws + (18u<<20));            // 4 MB
  char* aux = ws + (22u<<20);
  _Float16* w1f    = (_Float16*)aux;                       // 152,064 B
  _Float16* w2f    = (_Float16*)(aux + 152064);            // 39,168 B
  _Float16* fus_wf = (_Float16*)(aux + 152064 + 39168);    // 41,984 B
  float*    v2bg   = (float*)(aux + 233216);               // 8,192 B
  float*    bgmaxp = (float*)(aux + 241408);               // 128 B
  _Float16* whhp   = (_Float16*)(aux + 241536);            // 131,072 B
  float*    biasp  = (float*)(aux + 241536 + 131072);      // 2,048 B

  lstm_all<<<2368, 512, 0, stream>>>(target, neigh,
                                     enc_w_ih, enc_w_hh, enc_b_ih, enc_b_hh,
                                     nb_w_ih, nb_w_hh, nb_b_ih, nb_b_hh,
                                     h_enc16, h_nb16,
                                     w1, b1, w2, b2, fus_w,
                                     dec_w_ih, dec_w_hh, dec_b_ih, dec_b_hh,
                                     out_w, out_b,
                                     w1f, w2f, fus_wf, whhp, biasp, v2bg, bgmaxp);
  social_fuse<<<512, 512, 0, stream>>>(h_enc16, h_nb16, w1f, w2f, fus_wf,
                                       b1, v2bg, bgmaxp, fus_b, fusedp);
  dec_mfma<<<256, 512, 0, stream>>>(fusedp, whhp, biasp, dec_w_ih,
                                    out_w, out_b, (float*)d_out);
}